// Round 6
// baseline (1116.931 us; speedup 1.0000x reference)
//
#include <hip/hip_runtime.h>

// GConvLSTM single step x4 layers, H=C=0 => f-gate dead, peepholes dead.
// bf16 storage; parallel scan (R13); spmv unroll8 (R14).
// R16: XCD-congruent decode cut FETCH 163->33MB (L2-locality confirmed).
// R18: MFMA gates: async global_load_lds A-panels + fragment-linear B. Gates
// off the critical path.
// R19: atomic-free CSR build. k_scatter now #1 (206us): WRITE_SIZE 104MB for a
// 25.6MB edge array = 4x write amp. Cause: grid (x=p,y=b) => XCD = p%8, so all
// 8 XCDs write every bucket's 3.3MB region -> cross-XCD dirty-line stealing at
// the LLC coherence point.
// NEW R20: k_scatter on a 1-D grid, decode b=bid&7, p=bid>>3 => bucket==XCD.
// Each bucket's write region is owned by ONE XCD's L2: lines assemble locally,
// evict once. Chunk re-reads are LLC-absorbed (dst = 12.8MB << 256MB).

#define IN_CH 10
#define NBUK 8
#define PBLK 64
#define BUKN 12800  // NBUK*BUKN=102400 >= N=100000; LDS hist 51.2KB
typedef unsigned short u16;
typedef unsigned long long u64;
typedef short bf16x8 __attribute__((ext_vector_type(8)));
typedef float f32x4 __attribute__((ext_vector_type(4)));

struct __align__(8) Edge { int s; float w; };

__device__ __forceinline__ float bf2f(u16 u) { return __uint_as_float(((unsigned)u) << 16); }
__device__ __forceinline__ float lo16f(unsigned v) { return __uint_as_float(v << 16); }
__device__ __forceinline__ float hi16f(unsigned v) { return __uint_as_float(v & 0xffff0000u); }
__device__ __forceinline__ u16 f2bf(float f) {
    unsigned x = __float_as_uint(f);
    return (u16)((x + 0x7fff + ((x >> 16) & 1)) >> 16);  // RNE
}
__device__ __forceinline__ float ldv(const float* p) { return *p; }
__device__ __forceinline__ float ldv(const u16* p) { return bf2f(*p); }
__device__ __forceinline__ void stv(float* p, float v) { *p = v; }
__device__ __forceinline__ void stv(u16* p, float v) { *p = f2bf(v); }

// async global->LDS, 16B per lane. l must be wave-uniform; HW adds lane*16.
__device__ __forceinline__ void gload16(const u16* g, u16* l) {
    __builtin_amdgcn_global_load_lds(
        (const __attribute__((address_space(1))) unsigned*)(const void*)g,
        (__attribute__((address_space(3))) unsigned*)(void*)l, 16, 0, 0);
}

// ---------------- graph preprocessing: atomic-free CSR build ----------------

// per-(bucket,block) LDS partial histogram -> H[(b*PBLK+p)*BUKN + ln]
// grid (x=p, y=b): XCD = p%8 -> the 8 b-blocks of one chunk share an XCD
// (chunk read locality).
__global__ __launch_bounds__(256) void k_hist8(const int* __restrict__ dst,
                                               int* __restrict__ H, int e, int n) {
    __shared__ int sh[BUKN];
    const int p = blockIdx.x, b = blockIdx.y;
    const int lo = b * BUKN;
    const int hi = min(lo + BUKN, n);
    const int cl = hi - lo;
    for (int i = threadIdx.x; i < cl; i += 256) sh[i] = 0;
    __syncthreads();
    const int chunk = (e + PBLK - 1) / PBLK;
    const int e0 = p * chunk, e1 = min(e0 + chunk, e);
    for (int i = e0 + threadIdx.x; i < e1; i += 256) {
        int d = dst[i];
        if (d >= lo && d < hi) atomicAdd(&sh[d - lo], 1);
    }
    __syncthreads();
    int* Hb = H + (size_t)(b * PBLK + p) * BUKN;
    for (int i = threadIdx.x; i < cl; i += 256) Hb[i] = sh[i];
}

// cnt[node] = sum_p H[b,p,ln]
__global__ void k_hsum(const int* __restrict__ H, int* __restrict__ cnt, int n) {
    int t = blockIdx.x * 256 + threadIdx.x;
    if (t >= n) return;
    int b = t / BUKN, ln = t % BUKN;
    const int* Hb = H + (size_t)b * PBLK * BUKN + ln;
    int s = 0;
#pragma unroll 8
    for (int p = 0; p < PBLK; p++) s += Hb[(size_t)p * BUKN];
    cnt[t] = s;
}

// exclusive scan of the PBLK partials per node, seeded with row_ptr -> cursors in-place
__global__ void k_cseed(int* __restrict__ H, const int* __restrict__ row_ptr, int n) {
    int t = blockIdx.x * 256 + threadIdx.x;
    if (t >= n) return;
    int b = t / BUKN, ln = t % BUKN;
    int* Hb = H + (size_t)b * PBLK * BUKN + ln;
    int run = row_ptr[t];
#pragma unroll 4
    for (int p = 0; p < PBLK; p++) {
        int v = Hb[(size_t)p * BUKN];
        Hb[(size_t)p * BUKN] = run;
        run += v;
    }
}

// scatter edges using LDS cursors (no global atomics).
// 1-D grid, decode b=bid&7 (bucket==XCD), p=bid>>3: each bucket's 3.3MB CSR
// write region is owned by one XCD's L2 -> lines assemble locally, evict once.
__global__ __launch_bounds__(256) void k_scatter(const int* __restrict__ src,
                                                 const int* __restrict__ dst,
                                                 const float* __restrict__ dinv,
                                                 const int* __restrict__ H,
                                                 Edge* __restrict__ ed, int e, int n) {
    __shared__ int cur[BUKN];
    const int b = blockIdx.x & 7;
    const int p = blockIdx.x >> 3;
    const int lo = b * BUKN;
    const int hi = min(lo + BUKN, n);
    const int cl = hi - lo;
    const int* Cb = H + (size_t)(b * PBLK + p) * BUKN;
    for (int i = threadIdx.x; i < cl; i += 256) cur[i] = Cb[i];
    __syncthreads();
    const int chunk = (e + PBLK - 1) / PBLK;
    const int e0 = p * chunk, e1 = min(e0 + chunk, e);
    for (int i = e0 + threadIdx.x; i < e1; i += 256) {
        int d = dst[i];
        if (d >= lo && d < hi) {
            int s = src[i];
            int pos = atomicAdd(&cur[d - lo], 1);  // LDS atomic
            float w = dinv[s] * dinv[d];
            u64 v = (u64)(unsigned)s | ((u64)__float_as_uint(w) << 32);
            *(u64*)&ed[pos] = v;
        }
    }
}

__global__ void k_dinv(const int* __restrict__ cnt, float* __restrict__ dinv, int n) {
    int i = blockIdx.x * 256 + threadIdx.x;
    if (i < n) dinv[i] = cnt[i] > 0 ? rsqrtf((float)cnt[i]) : 0.f;
}

// ---- parallel scan: 1024 elems per 256-thread block ----

__global__ void k_bsum(const int* __restrict__ cnt, int* __restrict__ bsum, int n) {
    __shared__ int red[256];
    int t = threadIdx.x;
    int idx = blockIdx.x * 1024 + t * 4;
    int s = 0;
#pragma unroll
    for (int j = 0; j < 4; j++) s += (idx + j < n) ? cnt[idx + j] : 0;
    red[t] = s;
    __syncthreads();
    for (int off = 128; off > 0; off >>= 1) {
        if (t < off) red[t] += red[t + off];
        __syncthreads();
    }
    if (t == 0) bsum[blockIdx.x] = red[0];
}

__global__ __launch_bounds__(1024) void k_bscan(const int* __restrict__ bsum,
                                                int* __restrict__ boff,
                                                int* __restrict__ total_out, int B) {
    __shared__ int sh[1024];
    int t = threadIdx.x;
    int v = t < B ? bsum[t] : 0;
    sh[t] = v;
    __syncthreads();
    for (int off = 1; off < 1024; off <<= 1) {
        int x = (t >= off) ? sh[t - off] : 0;
        __syncthreads();
        sh[t] += x;
        __syncthreads();
    }
    if (t < B) boff[t] = sh[t] - v;  // exclusive
    if (t == B - 1) *total_out = sh[t];
}

__global__ void k_write(const int* __restrict__ cnt, const int* __restrict__ boff,
                        int* __restrict__ row_ptr, int* __restrict__ cursor, int n) {
    __shared__ int tsum[256];
    int t = threadIdx.x;
    int idx = blockIdx.x * 1024 + t * 4;
    int c[4];
    int s = 0;
#pragma unroll
    for (int j = 0; j < 4; j++) {
        c[j] = (idx + j < n) ? cnt[idx + j] : 0;
        s += c[j];
    }
    tsum[t] = s;
    __syncthreads();
    for (int off = 1; off < 256; off <<= 1) {
        int x = (t >= off) ? tsum[t - off] : 0;
        __syncthreads();
        tsum[t] += x;
        __syncthreads();
    }
    int run = boff[blockIdx.x] + tsum[t] - s;
#pragma unroll
    for (int j = 0; j < 4; j++) {
        if (idx + j < n) {
            row_ptr[idx + j] = run;
            cursor[idx + j] = run;
            run += c[j];
        }
    }
}

// ---------------- Cheb SpMV: full row, unroll x8 ----------------

template <int F>
__global__ void k_spmv(const u16* __restrict__ X, const u16* __restrict__ Tprev,
                       u16* __restrict__ Tout, const int* __restrict__ row_ptr,
                       const Edge* __restrict__ ed, int n, float scale) {
    int lane = threadIdx.x;  // [0, F/2)
    int node = blockIdx.x * blockDim.y + threadIdx.y;
    if (node >= n) return;
    int lo = row_ptr[node], hi = row_ptr[node + 1];
    const u16* Xc = X + 2 * lane;
    float a0[4] = {0.f, 0.f, 0.f, 0.f};
    float a1[4] = {0.f, 0.f, 0.f, 0.f};
    int e = lo;
    for (; e + 8 <= hi; e += 8) {
        Edge q[8];
#pragma unroll
        for (int j = 0; j < 8; j++) q[j] = ed[e + j];
        unsigned v[8];
#pragma unroll
        for (int j = 0; j < 8; j++)
            v[j] = *(const unsigned*)(Xc + (size_t)q[j].s * F);
#pragma unroll
        for (int j = 0; j < 8; j++) {
            a0[j & 3] = fmaf(q[j].w, lo16f(v[j]), a0[j & 3]);
            a1[j & 3] = fmaf(q[j].w, hi16f(v[j]), a1[j & 3]);
        }
    }
    for (; e + 4 <= hi; e += 4) {
        Edge q[4];
#pragma unroll
        for (int j = 0; j < 4; j++) q[j] = ed[e + j];
        unsigned v[4];
#pragma unroll
        for (int j = 0; j < 4; j++)
            v[j] = *(const unsigned*)(Xc + (size_t)q[j].s * F);
#pragma unroll
        for (int j = 0; j < 4; j++) {
            a0[j] = fmaf(q[j].w, lo16f(v[j]), a0[j]);
            a1[j] = fmaf(q[j].w, hi16f(v[j]), a1[j]);
        }
    }
    for (; e < hi; e++) {
        Edge q = ed[e];
        unsigned v = *(const unsigned*)(Xc + (size_t)q.s * F);
        a0[0] = fmaf(q.w, lo16f(v), a0[0]);
        a1[0] = fmaf(q.w, hi16f(v), a1[0]);
    }
    float v0 = -scale * ((a0[0] + a0[1]) + (a0[2] + a0[3]));
    float v1 = -scale * ((a1[0] + a1[1]) + (a1[2] + a1[3]));
    if (Tprev) {
        unsigned pv = *(const unsigned*)(Tprev + (size_t)node * F + 2 * lane);
        v0 -= lo16f(pv);
        v1 -= hi16f(pv);
    }
    *(unsigned*)(Tout + (size_t)node * F + 2 * lane) =
        (unsigned)f2bf(v0) | ((unsigned)f2bf(v1) << 16);
}

// ---------------- VALU chebgate (layers 0,1) ----------------
struct TP { const void* p[5]; };

template <typename ST, int FIN, int K>
__global__ __launch_bounds__(256) void k_chebgate(TP tp, const float* __restrict__ Wp,
                                                  const float* __restrict__ b4,
                                                  ST* __restrict__ H, int n, int F,
                                                  int F4pad) {
    __shared__ float As[FIN][68];
    __shared__ float Ws[FIN][128];
    const int tid = threadIdx.x;
    const int fx = tid & 31, ry = tid >> 5;
    const int row0 = blockIdx.y * 64;
    const int f0 = blockIdx.x * 32;
    const int f = f0 + fx;

    float acc[8][3];
    const float4 bv = *(const float4*)&b4[(size_t)f * 4];
#pragma unroll
    for (int r = 0; r < 8; r++) { acc[r][0] = bv.x; acc[r][1] = bv.y; acc[r][2] = bv.z; }

#pragma unroll
    for (int t = 0; t < K; t++) {
        const ST* T = (const ST*)tp.p[t];
        for (int idx = tid; idx < 64 * FIN; idx += 256) {
            int r = idx / FIN, a = idx - r * FIN;
            int rr = row0 + r;
            if (rr >= n) rr = n - 1;
            As[a][r] = ldv(&T[(size_t)rr * FIN + a]);
        }
        const float* Wt = Wp + (size_t)t * FIN * F4pad + (size_t)f0 * 4;
        for (int idx = tid; idx < FIN * 128; idx += 256) {
            int aa = idx >> 7, c = idx & 127;
            Ws[aa][c] = Wt[(size_t)aa * F4pad + c];
        }
        __syncthreads();
#pragma unroll 2
        for (int a = 0; a < FIN; a++) {
            const float4 w = *(const float4*)&Ws[a][fx * 4];
            const float4 x0 = *(const float4*)&As[a][ry * 8];
            const float4 x1 = *(const float4*)&As[a][ry * 8 + 4];
            const float xr[8] = {x0.x, x0.y, x0.z, x0.w, x1.x, x1.y, x1.z, x1.w};
#pragma unroll
            for (int r = 0; r < 8; r++) {
                acc[r][0] = fmaf(xr[r], w.x, acc[r][0]);
                acc[r][1] = fmaf(xr[r], w.y, acc[r][1]);
                acc[r][2] = fmaf(xr[r], w.z, acc[r][2]);
            }
        }
        __syncthreads();
    }

    if (f < F) {
#pragma unroll
        for (int r = 0; r < 8; r++) {
            int row = row0 + ry * 8 + r;
            if (row < n) {
                float gi = 1.f / (1.f + __expf(-acc[r][0]));
                float go = 1.f / (1.f + __expf(-acc[r][2]));
                float c = gi * tanhf(acc[r][1]);
                float h = go * tanhf(c);
                stv(&H[(size_t)row * F + f], fmaxf(h, 0.f));
            }
        }
    }
}

// ---------------- MFMA chebgate v2 (layer 2): LDS-staged A, fragment-linear B ----

template <int FIN, int K, int NT, int FPAD>
__global__ __launch_bounds__(256) void k_chebgate_mfma2(TP tp, const u16* __restrict__ Bp,
                                                        const float* __restrict__ b3,
                                                        u16* __restrict__ H, int n, int F,
                                                        int Hstride) {
    constexpr int NIT = K * FIN / 32;
    constexpr int CPR = FIN / 8;             // 16B chunks per A row
    constexpr int CSH = (CPR == 8) ? 3 : 2;
    constexpr int PANEL = 128 * FIN;         // u16 per tensor
    constexpr int IPT = (128 * CPR) / 256;   // gload16 per thread per tensor
    __shared__ __align__(16) u16 Alds[K * PANEL];

    const int tid = threadIdx.x;
    const int xb = blockIdx.x;
    const int wv = tid >> 6, lane = tid & 63;
    const int ln = lane & 15, lk = lane >> 4;
    const size_t panel_g = (size_t)xb * 128 * FIN;  // u16 offset into each tensor

    // ---- async stage: LDS linear, source pre-swizzled ----
#pragma unroll
    for (int t = 0; t < K; t++) {
        const u16* g = (const u16*)tp.p[t] + panel_g;
#pragma unroll
        for (int i = 0; i < IPT; i++) {
            int j0 = wv * (IPT * 64) + i * 64;   // wave-uniform chunk base
            int j = j0 + lane;
            int row = j >> CSH, c = j & (CPR - 1);
            int sc = (j & ~(CPR - 1)) | (c ^ (row & (CPR - 1)));
            gload16(g + (size_t)sc * 8, Alds + (size_t)t * PANEL + (size_t)j0 * 8);
        }
    }
    __syncthreads();

    const int r0 = xb * 128 + wv * 32;
    const u16* Bl = Bp + (size_t)lane * 8;

#pragma unroll 1
    for (int yb = 0; yb < NT; yb++) {
        f32x4 acc[2][2][3];
#pragma unroll
        for (int rt = 0; rt < 2; rt++)
#pragma unroll
            for (int s = 0; s < 2; s++)
#pragma unroll
                for (int g = 0; g < 3; g++) acc[rt][s][g] = (f32x4){0.f, 0.f, 0.f, 0.f};

#pragma unroll
        for (int it = 0; it < NIT; it++) {
            const int k0 = it * 32;
            const int t = k0 / FIN;
            const int a0 = k0 % FIN;
            bf16x8 af[2];
#pragma unroll
            for (int rt = 0; rt < 2; rt++) {
                int lrow = wv * 32 + rt * 16 + ln;
                int kc = (a0 >> 3) + lk;
                int kcs = kc ^ (lrow & (CPR - 1));
                af[rt] = *(const bf16x8*)(Alds + (size_t)t * PANEL + (size_t)lrow * FIN + kcs * 8);
            }
#pragma unroll
            for (int s = 0; s < 2; s++)
#pragma unroll
                for (int g = 0; g < 3; g++) {
                    int fi = (yb * NIT + it) * 6 + s * 3 + g;
                    bf16x8 bf = *(const bf16x8*)(Bl + (size_t)fi * 512);
#pragma unroll
                    for (int rt = 0; rt < 2; rt++)
                        acc[rt][s][g] = __builtin_amdgcn_mfma_f32_16x16x32_bf16(
                            af[rt], bf, acc[rt][s][g], 0, 0, 0);
                }
        }

        const int f0 = yb * 32;
#pragma unroll
        for (int s = 0; s < 2; s++) {
            int fcol = f0 + s * 16 + ln;
            if (fcol >= F) continue;
            float bi = b3[0 * FPAD + fcol];
            float bc = b3[1 * FPAD + fcol];
            float bo = b3[2 * FPAD + fcol];
#pragma unroll
            for (int rt = 0; rt < 2; rt++) {
#pragma unroll
                for (int reg = 0; reg < 4; reg++) {
                    int row = r0 + rt * 16 + lk * 4 + reg;
                    if (row < n) {
                        float gi = 1.f / (1.f + __expf(-(acc[rt][s][0][reg] + bi)));
                        float go = 1.f / (1.f + __expf(-(acc[rt][s][2][reg] + bo)));
                        float c = gi * tanhf(acc[rt][s][1][reg] + bc);
                        float h = go * tanhf(c);
                        H[(size_t)row * Hstride + fcol] = f2bf(fmaxf(h, 0.f));
                    }
                }
            }
        }
    }
}

// ---------------- MFMA chebgate v2 + fused final projection (layer 3) ----------------

template <int FIN, int K, int NT, int FPAD>
__global__ __launch_bounds__(256) void k_chebgate_mfma_fused2(
    TP tp, const u16* __restrict__ Bp, const float* __restrict__ b3,
    const float* __restrict__ W2, float* __restrict__ part, int n, int F) {
    constexpr int NIT = K * FIN / 32;
    constexpr int CPR = FIN / 8;
    constexpr int CSH = (CPR == 8) ? 3 : 2;
    constexpr int PANEL = 128 * FIN;
    constexpr int IPT = (128 * CPR) / 256;
    __shared__ __align__(16) u16 Alds[K * PANEL];

    const int tid = threadIdx.x;
    const int xb = blockIdx.x;
    const int wv = tid >> 6, lane = tid & 63;
    const int ln = lane & 15, lk = lane >> 4;
    const size_t panel_g = (size_t)xb * 128 * FIN;

#pragma unroll
    for (int t = 0; t < K; t++) {
        const u16* g = (const u16*)tp.p[t] + panel_g;
#pragma unroll
        for (int i = 0; i < IPT; i++) {
            int j0 = wv * (IPT * 64) + i * 64;
            int j = j0 + lane;
            int row = j >> CSH, c = j & (CPR - 1);
            int sc = (j & ~(CPR - 1)) | (c ^ (row & (CPR - 1)));
            gload16(g + (size_t)sc * 8, Alds + (size_t)t * PANEL + (size_t)j0 * 8);
        }
    }
    __syncthreads();

    const int r0 = xb * 128 + wv * 32;
    const u16* Bl = Bp + (size_t)lane * 8;

#pragma unroll 1
    for (int yb = 0; yb < NT; yb++) {
        f32x4 acc[2][2][3];
#pragma unroll
        for (int rt = 0; rt < 2; rt++)
#pragma unroll
            for (int s = 0; s < 2; s++)
#pragma unroll
                for (int g = 0; g < 3; g++) acc[rt][s][g] = (f32x4){0.f, 0.f, 0.f, 0.f};

#pragma unroll
        for (int it = 0; it < NIT; it++) {
            const int k0 = it * 32;
            const int t = k0 / FIN;
            const int a0 = k0 % FIN;
            bf16x8 af[2];
#pragma unroll
            for (int rt = 0; rt < 2; rt++) {
                int lrow = wv * 32 + rt * 16 + ln;
                int kc = (a0 >> 3) + lk;
                int kcs = kc ^ (lrow & (CPR - 1));
                af[rt] = *(const bf16x8*)(Alds + (size_t)t * PANEL + (size_t)lrow * FIN + kcs * 8);
            }
#pragma unroll
            for (int s = 0; s < 2; s++)
#pragma unroll
                for (int g = 0; g < 3; g++) {
                    int fi = (yb * NIT + it) * 6 + s * 3 + g;
                    bf16x8 bf = *(const bf16x8*)(Bl + (size_t)fi * 512);
#pragma unroll
                    for (int rt = 0; rt < 2; rt++)
                        acc[rt][s][g] = __builtin_amdgcn_mfma_f32_16x16x32_bf16(
                            af[rt], bf, acc[rt][s][g], 0, 0, 0);
                }
        }

        // epilogue + fused projection for this f-tile
        const int f0 = yb * 32;
        float p0[2][4], p1[2][4];
#pragma unroll
        for (int rt = 0; rt < 2; rt++)
#pragma unroll
            for (int reg = 0; reg < 4; reg++) { p0[rt][reg] = 0.f; p1[rt][reg] = 0.f; }

#pragma unroll
        for (int s = 0; s < 2; s++) {
            int fcol = f0 + s * 16 + ln;
            float w20 = fcol < F ? W2[fcol * 2 + 0] : 0.f;
            float w21 = fcol < F ? W2[fcol * 2 + 1] : 0.f;
            float bi = b3[0 * FPAD + fcol];
            float bc = b3[1 * FPAD + fcol];
            float bo = b3[2 * FPAD + fcol];
#pragma unroll
            for (int rt = 0; rt < 2; rt++) {
#pragma unroll
                for (int reg = 0; reg < 4; reg++) {
                    float gi = 1.f / (1.f + __expf(-(acc[rt][s][0][reg] + bi)));
                    float go = 1.f / (1.f + __expf(-(acc[rt][s][2][reg] + bo)));
                    float c = gi * tanhf(acc[rt][s][1][reg] + bc);
                    float h = fmaxf(go * tanhf(c), 0.f);
                    p0[rt][reg] = fmaf(h, w20, p0[rt][reg]);
                    p1[rt][reg] = fmaf(h, w21, p1[rt][reg]);
                }
            }
        }

#pragma unroll
        for (int rt = 0; rt < 2; rt++) {
#pragma unroll
            for (int reg = 0; reg < 4; reg++) {
                float v0 = p0[rt][reg], v1 = p1[rt][reg];
#pragma unroll
                for (int m = 1; m <= 8; m <<= 1) {
                    v0 += __shfl_xor(v0, m);
                    v1 += __shfl_xor(v1, m);
                }
                p0[rt][reg] = v0;
                p1[rt][reg] = v1;
            }
        }

        if (ln == 0) {
#pragma unroll
            for (int rt = 0; rt < 2; rt++) {
#pragma unroll
                for (int reg = 0; reg < 4; reg++) {
                    int row = r0 + rt * 16 + lk * 4 + reg;
                    if (row < n) {
                        float* pp = part + ((size_t)yb * n + row) * 2;
                        pp[0] = p0[rt][reg];
                        pp[1] = p1[rt][reg];
                    }
                }
            }
        }
    }
}

// ---------------- partial-sum + softmax ----------------
__global__ void k_smax(const float* __restrict__ part, const float* __restrict__ b,
                       float* __restrict__ out, int n, int ntiles) {
    int i = blockIdx.x * 256 + threadIdx.x;
    if (i >= n) return;
    float l0 = b[0], l1 = b[1];
    for (int t = 0; t < ntiles; t++) {
        const float* pp = part + ((size_t)t * n + i) * 2;
        l0 += pp[0];
        l1 += pp[1];
    }
    float m = fmaxf(l0, l1);
    float e0 = __expf(l0 - m), e1 = __expf(l1 - m);
    float s = 1.f / (e0 + e1);
    out[(size_t)i * 2 + 0] = e0 * s;
    out[(size_t)i * 2 + 1] = e1 * s;
}

// ---------------- weight/bias packing ----------------

__global__ void k_pack_w(const float* __restrict__ Wi, const float* __restrict__ Wc,
                         const float* __restrict__ Wo, float* __restrict__ Wp,
                         int KFIN, int F, int F4pad) {
    int idx = blockIdx.x * 256 + threadIdx.x;
    int tot = KFIN * F4pad;
    if (idx >= tot) return;
    int c = idx % F4pad;
    int ka = idx / F4pad;
    int f = c >> 2, g = c & 3;
    float v = 0.f;
    if (g < 3 && f < F) {
        const float* Wg = (g == 0) ? Wi : ((g == 1) ? Wc : Wo);
        v = Wg[(size_t)ka * F + f];
    }
    Wp[idx] = v;
}

__global__ void k_pack_b(const float* __restrict__ bxi, const float* __restrict__ bhi,
                         const float* __restrict__ bi, const float* __restrict__ bxc,
                         const float* __restrict__ bhc, const float* __restrict__ bc,
                         const float* __restrict__ bxo, const float* __restrict__ bho,
                         const float* __restrict__ bo, float* __restrict__ b4,
                         int F, int F4pad) {
    int idx = blockIdx.x * 256 + threadIdx.x;
    if (idx >= F4pad) return;
    int f = idx >> 2, g = idx & 3;
    float v = 0.f;
    if (g < 3 && f < F) {
        if (g == 0) v = bxi[f] + bhi[f] + bi[f];
        else if (g == 1) v = bxc[f] + bhc[f] + bc[f];
        else v = bxo[f] + bho[f] + bo[f];
    }
    b4[idx] = v;
}

// fragment-linear pack: Bp[yb][it][s*3+g][lane][8], lane=(lk<<4)|ln
// element (lane,j) = W_g[k = it*32 + lk*8 + j][fcol = yb*32 + s*16 + ln]
__global__ void k_pack_wf(const float* __restrict__ Wi, const float* __restrict__ Wc,
                          const float* __restrict__ Wo, u16* __restrict__ Bp,
                          int NIT, int Fin, int F, int NT) {
    int idx = blockIdx.x * 256 + threadIdx.x;
    int tot = NT * NIT * 6 * 512;
    if (idx >= tot) return;
    int frag = idx >> 9;
    int r = idx & 511;
    int lane = r >> 3, j = r & 7;
    int lk = lane >> 4, ln = lane & 15;
    int yb = frag / (NIT * 6);
    int q = frag % (NIT * 6);
    int it = q / 6, sg = q % 6;
    int s = sg / 3, g = sg % 3;
    int fcol = yb * 32 + s * 16 + ln;
    int k = it * 32 + lk * 8 + j;
    int t = k / Fin, a = k % Fin;
    float v = 0.f;
    if (fcol < F) {
        const float* Wg = (g == 0) ? Wi : ((g == 1) ? Wc : Wo);
        v = Wg[((size_t)t * Fin + a) * F + fcol];
    }
    Bp[idx] = f2bf(v);
}

__global__ void k_pack_b3(const float* __restrict__ bxi, const float* __restrict__ bhi,
                          const float* __restrict__ bi, const float* __restrict__ bxc,
                          const float* __restrict__ bhc, const float* __restrict__ bc,
                          const float* __restrict__ bxo, const float* __restrict__ bho,
                          const float* __restrict__ bo, float* __restrict__ b3,
                          int F, int FPAD) {
    int idx = blockIdx.x * 256 + threadIdx.x;
    if (idx >= 3 * FPAD) return;
    int g = idx / FPAD, f = idx % FPAD;
    float v = 0.f;
    if (f < F) {
        if (g == 0) v = bxi[f] + bhi[f] + bi[f];
        else if (g == 1) v = bxc[f] + bhc[f] + bc[f];
        else v = bxo[f] + bho[f] + bo[f];
    }
    b3[idx] = v;
}

__global__ void k_cvt(const float* __restrict__ x, u16* __restrict__ y, int n) {
    int i = blockIdx.x * 256 + threadIdx.x;
    if (i < n) y[i] = f2bf(x[i]);
}

// ---------------- launch ----------------

static inline size_t al(size_t x) { return (x + 255) & ~(size_t)255; }

extern "C" void kernel_launch(void* const* d_in, const int* in_sizes, int n_in,
                              void* d_out, int out_size, void* d_ws, size_t ws_size,
                              hipStream_t stream) {
    const float* X0 = (const float*)d_in[0];
    const int* ei = (const int*)d_in[1];
    const int N = in_sizes[0] / IN_CH;
    const int E = in_sizes[1] / 2;
    const int* src = ei;
    const int* dst = ei + E;

    // ---- workspace carve (~122 MB) ----
    char* p = (char*)d_ws;
    size_t off = 0;
    auto carve = [&](size_t bytes) -> char* { char* r = p + off; off += al(bytes); return r; };
    int* row_ptr  = (int*)carve((size_t)(N + 1) * 4);
    int* cnt      = (int*)carve((size_t)N * 4);
    int* cursor   = (int*)carve((size_t)N * 4);
    float* dinv   = (float*)carve((size_t)N * 4);
    int* bsum     = (int*)carve((size_t)1024 * 4);
    int* boff     = (int*)carve((size_t)1024 * 4);
    Edge* edges   = (Edge*)carve((size_t)E * 8);
    const size_t S64 = al((size_t)N * 64 * 2);
    char* bufA    = carve(5 * S64);               // 64 MB
    char* bufB    = carve((size_t)N * 304);       // 30.4 MB
    float* Wp     = (float*)carve((size_t)48 * 128 * 4);
    float* b4     = (float*)carve((size_t)128 * 4);
    u16* Wt       = (u16*)carve((size_t)480 * 320 * 2);
    float* b3     = (float*)carve((size_t)480 * 4);
    (void)ws_size;

    u16* X0c  = (u16*)bufA;                                   // N x 10
    u16* T0_1 = (u16*)(bufA + al((size_t)N * 20));            // N x 10
    u16* H0   = (u16*)(bufA + S64);                           // N x 16
    u16* T1_1 = (u16*)(bufA + S64 + al((size_t)N * 32));      // N x 16
    u16* T1_2 = (u16*)(bufA + S64 + 2 * al((size_t)N * 32));  // N x 16
    u16* L2T[4];
    for (int t = 0; t < 4; t++) L2T[t] = (u16*)(bufB + t * al((size_t)N * 64));
    u16* L3T[5];
    for (int t = 0; t < 5; t++) L3T[t] = (u16*)(bufA + t * S64);
    float* part = (float*)bufB;                               // 5 x N x 2 fp32 (4 MB)
    int* Hh = (int*)bufB;  // 26.2 MB partial hist/cursors; bufB dead until layer 2

    // ---- graph preprocessing: atomic-free CSR ----
    int gN = (N + 255) / 256;
    int B = (N + 1023) / 1024;
    dim3 gh(PBLK, NBUK);
    k_hist8<<<gh, 256, 0, stream>>>(dst, Hh, E, N);
    k_hsum<<<gN, 256, 0, stream>>>(Hh, cnt, N);
    k_dinv<<<gN, 256, 0, stream>>>(cnt, dinv, N);
    k_bsum<<<B, 256, 0, stream>>>(cnt, bsum, N);
    k_bscan<<<1, 1024, 0, stream>>>(bsum, boff, row_ptr + N, B);
    k_write<<<B, 256, 0, stream>>>(cnt, boff, row_ptr, cursor, N);
    k_cseed<<<gN, 256, 0, stream>>>(Hh, row_ptr, N);
    k_scatter<<<PBLK * NBUK, 256, 0, stream>>>(src, dst, dinv, Hh, edges, E, N);

    k_cvt<<<(N * IN_CH + 255) / 256, 256, 0, stream>>>(X0, X0c, N * IN_CH);

    dim3 gv(1, (N + 63) / 64);
    int rb = (N + 127) / 128;

    // spmv shapes: LPN = F/2 lanes per node
    dim3 bs5(5, 48);   int g5 = (N + 47) / 48;
    dim3 bs8(8, 32);   int g8 = (N + 31) / 32;
    dim3 bs16(16, 16); int g16 = (N + 15) / 16;
    dim3 bs32(32, 8);  int g32 = (N + 7) / 8;

    // ---- layer 0: VALU, K=2, Fin=10, F=16 ----
    {
        k_pack_w<<<(20 * 128 + 255) / 256, 256, 0, stream>>>(
            (const float*)d_in[2], (const float*)d_in[10], (const float*)d_in[14], Wp, 20, 16, 128);
        k_pack_b<<<1, 256, 0, stream>>>(
            (const float*)d_in[3], (const float*)d_in[4], (const float*)d_in[5],
            (const float*)d_in[11], (const float*)d_in[12], (const float*)d_in[13],
            (const float*)d_in[15], (const float*)d_in[16], (const float*)d_in[17], b4, 16, 128);
        k_spmv<10><<<g5, bs5, 0, stream>>>(X0c, nullptr, T0_1, row_ptr, edges, N, 1.f);
        TP tp; tp.p[0] = X0c; tp.p[1] = T0_1;
        k_chebgate<u16, 10, 2><<<gv, 256, 0, stream>>>(tp, Wp, b4, H0, N, 16, 128);
    }
    // ---- layer 1: VALU, K=3, Fin=16, F=32 ----
    {
        k_pack_w<<<(48 * 128 + 255) / 256, 256, 0, stream>>>(
            (const float*)d_in[18], (const float*)d_in[26], (const float*)d_in[30], Wp, 48, 32, 128);
        k_pack_b<<<1, 256, 0, stream>>>(
            (const float*)d_in[19], (const float*)d_in[20], (const float*)d_in[21],
            (const float*)d_in[27], (const float*)d_in[28], (const float*)d_in[29],
            (const float*)d_in[31], (const float*)d_in[32], (const float*)d_in[33], b4, 32, 128);
        k_spmv<16><<<g8, bs8, 0, stream>>>(H0, nullptr, T1_1, row_ptr, edges, N, 1.f);
        k_spmv<16><<<g8, bs8, 0, stream>>>(T1_1, H0, T1_2, row_ptr, edges, N, 2.f);
        TP tp; tp.p[0] = H0; tp.p[1] = T1_1; tp.p[2] = T1_2;
        k_chebgate<u16, 16, 3><<<gv, 256, 0, stream>>>(tp, Wp, b4, L2T[0], N, 32, 128);
    }
    // ---- layer 2: MFMA v2, K=4, Fin=32, F=64, NT=2 ----
    {
        // NIT = 4*32/32 = 4; Bp size = 2*4*6*512 halfwords = 48 KB
        k_pack_wf<<<(2 * 4 * 6 * 512 + 255) / 256, 256, 0, stream>>>(
            (const float*)d_in[34], (const float*)d_in[42], (const float*)d_in[46], Wt, 4, 32, 64, 2);
        k_pack_b3<<<1, 256, 0, stream>>>(
            (const float*)d_in[35], (const float*)d_in[36], (const float*)d_in[37],
            (const float*)d_in[43], (const float*)d_in[44], (const float*)d_in[45],
            (const float*)d_in[47], (const float*)d_in[48], (const float*)d_in[49], b3, 64, 64);
        k_spmv<32><<<g16, bs16, 0, stream>>>(L2T[0], nullptr, L2T[1], row_ptr, edges, N, 1.f);
        k_spmv<32><<<g16, bs16, 0, stream>>>(L2T[1], L2T[0], L2T[2], row_ptr, edges, N, 2.f);
        k_spmv<32><<<g16, bs16, 0, stream>>>(L2T[2], L2T[1], L2T[3], row_ptr, edges, N, 2.f);
        TP tp; for (int t = 0; t < 4; t++) tp.p[t] = L2T[t];
        k_chebgate_mfma2<32, 4, 2, 64><<<rb, 256, 0, stream>>>(tp, Wt, b3, L3T[0], N, 64, 64);
    }
    // ---- layer 3: MFMA v2 + fused final projection, K=5, Fin=64, F=152, NT=5 ----
    {
        // NIT = 5*64/32 = 10; Bp size = 5*10*6*512 halfwords = 300 KB
        k_pack_wf<<<(5 * 10 * 6 * 512 + 255) / 256, 256, 0, stream>>>(
            (const float*)d_in[50], (const float*)d_in[58], (const float*)d_in[62], Wt, 10, 64, 152, 5);
        k_pack_b3<<<2, 256, 0, stream>>>(
            (const float*)d_in[51], (const float*)d_in[52], (const float*)d_in[53],
            (const float*)d_in[59], (const float*)d_in[60], (const float*)d_in[61],
            (const float*)d_in[63], (const float*)d_in[64], (const float*)d_in[65], b3, 152, 160);
        k_spmv<64><<<g32, bs32, 0, stream>>>(L3T[0], nullptr, L3T[1], row_ptr, edges, N, 1.f);
        k_spmv<64><<<g32, bs32, 0, stream>>>(L3T[1], L3T[0], L3T[2], row_ptr, edges, N, 2.f);
        k_spmv<64><<<g32, bs32, 0, stream>>>(L3T[2], L3T[1], L3T[3], row_ptr, edges, N, 2.f);
        k_spmv<64><<<g32, bs32, 0, stream>>>(L3T[3], L3T[2], L3T[4], row_ptr, edges, N, 2.f);
        TP tp; for (int t = 0; t < 5; t++) tp.p[t] = L3T[t];
        k_chebgate_mfma_fused2<64, 5, 5, 160><<<rb, 256, 0, stream>>>(
            tp, Wt, b3, (const float*)d_in[66], part, N, 152);
    }

    k_smax<<<gN, 256, 0, stream>>>(part, (const float*)d_in[67], (float*)d_out, N, 5);
}

// Round 7
// 1033.478 us; speedup vs baseline: 1.0807x; 1.0807x over previous
//
#include <hip/hip_runtime.h>

// GConvLSTM single step x4 layers, H=C=0 => f-gate dead, peepholes dead.
// bf16 storage; parallel scan (R13); spmv unroll8 (R14).
// R16: XCD-congruent decode cut FETCH 163->33MB (L2-locality confirmed).
// R18: MFMA gates: async global_load_lds A-panels + fragment-linear B.
// R19: atomic-free CSR. R20 (bucket==XCD scatter) FAILED: FETCH 26->113MB
// (chunk read on 8 XCDs), WRITE 104->132MB — partial 64B lines written by ~16
// interleaved blocks get evicted before assembly; XCD ownership can't fix that.
// NEW R21: single-writer CSR build (counting sort, 2 passes):
//   k_bcount: per-chunk per-bucket counts (read dst once)
//   k_boff:   prefix -> staging offsets (tiny)
//   k_stage:  edges -> bucket-major staging, sequential per-(p,b) segment (amp~1)
//   k_bknt:   per-node counts from staged dst (one block per 256-node bucket)
//   scan ->   row_ptr (unchanged kernels)
//   k_bscat:  one block per bucket scatters its ~8K edges into its OWN 64KB
//             CSR region (single writer, L2-resident -> lines evict once).
// Deletes k_hist8/k_hsum/k_cseed/k_scatter (8x reads + strided RMW + stolen lines).

#define IN_CH 10
#define PCH 128     // staging chunks
#define NB2MAX 512  // max buckets (N<=131072)
typedef unsigned short u16;
typedef unsigned long long u64;
typedef short bf16x8 __attribute__((ext_vector_type(8)));
typedef float f32x4 __attribute__((ext_vector_type(4)));

struct __align__(8) Edge { int s; float w; };

__device__ __forceinline__ float bf2f(u16 u) { return __uint_as_float(((unsigned)u) << 16); }
__device__ __forceinline__ float lo16f(unsigned v) { return __uint_as_float(v << 16); }
__device__ __forceinline__ float hi16f(unsigned v) { return __uint_as_float(v & 0xffff0000u); }
__device__ __forceinline__ u16 f2bf(float f) {
    unsigned x = __float_as_uint(f);
    return (u16)((x + 0x7fff + ((x >> 16) & 1)) >> 16);  // RNE
}
__device__ __forceinline__ float ldv(const float* p) { return *p; }
__device__ __forceinline__ float ldv(const u16* p) { return bf2f(*p); }
__device__ __forceinline__ void stv(float* p, float v) { *p = v; }
__device__ __forceinline__ void stv(u16* p, float v) { *p = f2bf(v); }

// async global->LDS, 16B per lane. l must be wave-uniform; HW adds lane*16.
__device__ __forceinline__ void gload16(const u16* g, u16* l) {
    __builtin_amdgcn_global_load_lds(
        (const __attribute__((address_space(1))) unsigned*)(const void*)g,
        (__attribute__((address_space(3))) unsigned*)(void*)l, 16, 0, 0);
}

// ---------------- graph preprocessing: single-writer CSR build ----------------
// bucket = node >> 8 (256 nodes per bucket)

// per-chunk per-bucket counts: C[b*PCH + p]
__global__ __launch_bounds__(256) void k_bcount(const int* __restrict__ dst,
                                                int* __restrict__ C, int e, int nb2) {
    __shared__ int sh[NB2MAX];
    const int p = blockIdx.x;
    for (int i = threadIdx.x; i < nb2; i += 256) sh[i] = 0;
    __syncthreads();
    const int chunk = (e + PCH - 1) / PCH;
    const int e0 = p * chunk, e1 = min(e0 + chunk, e);
    for (int i = e0 + threadIdx.x; i < e1; i += 256)
        atomicAdd(&sh[dst[i] >> 8], 1);
    __syncthreads();
    for (int b = threadIdx.x; b < nb2; b += 256) C[b * PCH + p] = sh[b];
}

// prefix: C[b][p] -> global staging offset; seg[b] = bucket segment start
__global__ __launch_bounds__(512) void k_boff(int* __restrict__ C, int* __restrict__ seg,
                                              int nb2) {
    __shared__ int sh[512];
    const int t = threadIdx.x;
    int tot = 0;
    if (t < nb2) {
        int* Cb = C + (size_t)t * PCH;
        int run = 0;
#pragma unroll 4
        for (int p = 0; p < PCH; p++) { int v = Cb[p]; Cb[p] = run; run += v; }
        tot = run;
    }
    sh[t] = tot;
    __syncthreads();
    for (int off = 1; off < 512; off <<= 1) {
        int x = (t >= off) ? sh[t - off] : 0;
        __syncthreads();
        sh[t] += x;
        __syncthreads();
    }
    const int base = sh[t] - tot;  // exclusive
    if (t < nb2) {
        seg[t] = base;
        int* Cb = C + (size_t)t * PCH;
#pragma unroll 4
        for (int p = 0; p < PCH; p++) Cb[p] += base;
        if (t == nb2 - 1) seg[nb2] = base + tot;
    }
}

// stage edges bucket-major: sequential append per (p,b) segment (write amp ~1)
__global__ __launch_bounds__(256) void k_stage(const int* __restrict__ src,
                                               const int* __restrict__ dst,
                                               const int* __restrict__ C,
                                               int* __restrict__ Sd, int* __restrict__ Ss,
                                               int e, int nb2) {
    __shared__ int cur[NB2MAX];
    const int p = blockIdx.x;
    for (int i = threadIdx.x; i < nb2; i += 256) cur[i] = C[(size_t)i * PCH + p];
    __syncthreads();
    const int chunk = (e + PCH - 1) / PCH;
    const int e0 = p * chunk, e1 = min(e0 + chunk, e);
    for (int i = e0 + threadIdx.x; i < e1; i += 256) {
        int d = dst[i], s = src[i];
        int pos = atomicAdd(&cur[d >> 8], 1);
        Sd[pos] = d;
        Ss[pos] = s;
    }
}

// per-node counts from staged dst: one block per bucket
__global__ __launch_bounds__(256) void k_bknt(const int* __restrict__ Sd,
                                              const int* __restrict__ seg,
                                              int* __restrict__ cnt, int n) {
    __shared__ int sh[256];
    const int b = blockIdx.x;
    sh[threadIdx.x] = 0;
    __syncthreads();
    const int lo = seg[b], hi = seg[b + 1];
    for (int i = lo + threadIdx.x; i < hi; i += 256)
        atomicAdd(&sh[Sd[i] & 255], 1);
    __syncthreads();
    int node = b * 256 + threadIdx.x;
    if (node < n) cnt[node] = sh[threadIdx.x];
}

// final scatter: one block per bucket writes its OWN 64KB CSR region
__global__ __launch_bounds__(256) void k_bscat(const int* __restrict__ Sd,
                                               const int* __restrict__ Ss,
                                               const int* __restrict__ seg,
                                               const int* __restrict__ row_ptr,
                                               const float* __restrict__ dinv,
                                               Edge* __restrict__ ed, int n) {
    __shared__ int cur[256];
    const int b = blockIdx.x;
    int node = b * 256 + threadIdx.x;
    cur[threadIdx.x] = node < n ? row_ptr[node] : 0;
    __syncthreads();
    const int lo = seg[b], hi = seg[b + 1];
    for (int i = lo + threadIdx.x; i < hi; i += 256) {
        int d = Sd[i], s = Ss[i];
        int pos = atomicAdd(&cur[d & 255], 1);  // LDS atomic
        float w = dinv[s] * dinv[d];
        u64 v = (u64)(unsigned)s | ((u64)__float_as_uint(w) << 32);
        *(u64*)&ed[pos] = v;
    }
}

__global__ void k_dinv(const int* __restrict__ cnt, float* __restrict__ dinv, int n) {
    int i = blockIdx.x * 256 + threadIdx.x;
    if (i < n) dinv[i] = cnt[i] > 0 ? rsqrtf((float)cnt[i]) : 0.f;
}

// ---- parallel scan: 1024 elems per 256-thread block ----

__global__ void k_bsum(const int* __restrict__ cnt, int* __restrict__ bsum, int n) {
    __shared__ int red[256];
    int t = threadIdx.x;
    int idx = blockIdx.x * 1024 + t * 4;
    int s = 0;
#pragma unroll
    for (int j = 0; j < 4; j++) s += (idx + j < n) ? cnt[idx + j] : 0;
    red[t] = s;
    __syncthreads();
    for (int off = 128; off > 0; off >>= 1) {
        if (t < off) red[t] += red[t + off];
        __syncthreads();
    }
    if (t == 0) bsum[blockIdx.x] = red[0];
}

__global__ __launch_bounds__(1024) void k_bscan(const int* __restrict__ bsum,
                                                int* __restrict__ boff,
                                                int* __restrict__ total_out, int B) {
    __shared__ int sh[1024];
    int t = threadIdx.x;
    int v = t < B ? bsum[t] : 0;
    sh[t] = v;
    __syncthreads();
    for (int off = 1; off < 1024; off <<= 1) {
        int x = (t >= off) ? sh[t - off] : 0;
        __syncthreads();
        sh[t] += x;
        __syncthreads();
    }
    if (t < B) boff[t] = sh[t] - v;  // exclusive
    if (t == B - 1) *total_out = sh[t];
}

__global__ void k_write(const int* __restrict__ cnt, const int* __restrict__ boff,
                        int* __restrict__ row_ptr, int* __restrict__ cursor, int n) {
    __shared__ int tsum[256];
    int t = threadIdx.x;
    int idx = blockIdx.x * 1024 + t * 4;
    int c[4];
    int s = 0;
#pragma unroll
    for (int j = 0; j < 4; j++) {
        c[j] = (idx + j < n) ? cnt[idx + j] : 0;
        s += c[j];
    }
    tsum[t] = s;
    __syncthreads();
    for (int off = 1; off < 256; off <<= 1) {
        int x = (t >= off) ? tsum[t - off] : 0;
        __syncthreads();
        tsum[t] += x;
        __syncthreads();
    }
    int run = boff[blockIdx.x] + tsum[t] - s;
#pragma unroll
    for (int j = 0; j < 4; j++) {
        if (idx + j < n) {
            row_ptr[idx + j] = run;
            cursor[idx + j] = run;
            run += c[j];
        }
    }
}

// ---------------- Cheb SpMV: full row, unroll x8 ----------------

template <int F>
__global__ void k_spmv(const u16* __restrict__ X, const u16* __restrict__ Tprev,
                       u16* __restrict__ Tout, const int* __restrict__ row_ptr,
                       const Edge* __restrict__ ed, int n, float scale) {
    int lane = threadIdx.x;  // [0, F/2)
    int node = blockIdx.x * blockDim.y + threadIdx.y;
    if (node >= n) return;
    int lo = row_ptr[node], hi = row_ptr[node + 1];
    const u16* Xc = X + 2 * lane;
    float a0[4] = {0.f, 0.f, 0.f, 0.f};
    float a1[4] = {0.f, 0.f, 0.f, 0.f};
    int e = lo;
    for (; e + 8 <= hi; e += 8) {
        Edge q[8];
#pragma unroll
        for (int j = 0; j < 8; j++) q[j] = ed[e + j];
        unsigned v[8];
#pragma unroll
        for (int j = 0; j < 8; j++)
            v[j] = *(const unsigned*)(Xc + (size_t)q[j].s * F);
#pragma unroll
        for (int j = 0; j < 8; j++) {
            a0[j & 3] = fmaf(q[j].w, lo16f(v[j]), a0[j & 3]);
            a1[j & 3] = fmaf(q[j].w, hi16f(v[j]), a1[j & 3]);
        }
    }
    for (; e + 4 <= hi; e += 4) {
        Edge q[4];
#pragma unroll
        for (int j = 0; j < 4; j++) q[j] = ed[e + j];
        unsigned v[4];
#pragma unroll
        for (int j = 0; j < 4; j++)
            v[j] = *(const unsigned*)(Xc + (size_t)q[j].s * F);
#pragma unroll
        for (int j = 0; j < 4; j++) {
            a0[j] = fmaf(q[j].w, lo16f(v[j]), a0[j]);
            a1[j] = fmaf(q[j].w, hi16f(v[j]), a1[j]);
        }
    }
    for (; e < hi; e++) {
        Edge q = ed[e];
        unsigned v = *(const unsigned*)(Xc + (size_t)q.s * F);
        a0[0] = fmaf(q.w, lo16f(v), a0[0]);
        a1[0] = fmaf(q.w, hi16f(v), a1[0]);
    }
    float v0 = -scale * ((a0[0] + a0[1]) + (a0[2] + a0[3]));
    float v1 = -scale * ((a1[0] + a1[1]) + (a1[2] + a1[3]));
    if (Tprev) {
        unsigned pv = *(const unsigned*)(Tprev + (size_t)node * F + 2 * lane);
        v0 -= lo16f(pv);
        v1 -= hi16f(pv);
    }
    *(unsigned*)(Tout + (size_t)node * F + 2 * lane) =
        (unsigned)f2bf(v0) | ((unsigned)f2bf(v1) << 16);
}

// ---------------- VALU chebgate (layers 0,1) ----------------
struct TP { const void* p[5]; };

template <typename ST, int FIN, int K>
__global__ __launch_bounds__(256) void k_chebgate(TP tp, const float* __restrict__ Wp,
                                                  const float* __restrict__ b4,
                                                  ST* __restrict__ H, int n, int F,
                                                  int F4pad) {
    __shared__ float As[FIN][68];
    __shared__ float Ws[FIN][128];
    const int tid = threadIdx.x;
    const int fx = tid & 31, ry = tid >> 5;
    const int row0 = blockIdx.y * 64;
    const int f0 = blockIdx.x * 32;
    const int f = f0 + fx;

    float acc[8][3];
    const float4 bv = *(const float4*)&b4[(size_t)f * 4];
#pragma unroll
    for (int r = 0; r < 8; r++) { acc[r][0] = bv.x; acc[r][1] = bv.y; acc[r][2] = bv.z; }

#pragma unroll
    for (int t = 0; t < K; t++) {
        const ST* T = (const ST*)tp.p[t];
        for (int idx = tid; idx < 64 * FIN; idx += 256) {
            int r = idx / FIN, a = idx - r * FIN;
            int rr = row0 + r;
            if (rr >= n) rr = n - 1;
            As[a][r] = ldv(&T[(size_t)rr * FIN + a]);
        }
        const float* Wt = Wp + (size_t)t * FIN * F4pad + (size_t)f0 * 4;
        for (int idx = tid; idx < FIN * 128; idx += 256) {
            int aa = idx >> 7, c = idx & 127;
            Ws[aa][c] = Wt[(size_t)aa * F4pad + c];
        }
        __syncthreads();
#pragma unroll 2
        for (int a = 0; a < FIN; a++) {
            const float4 w = *(const float4*)&Ws[a][fx * 4];
            const float4 x0 = *(const float4*)&As[a][ry * 8];
            const float4 x1 = *(const float4*)&As[a][ry * 8 + 4];
            const float xr[8] = {x0.x, x0.y, x0.z, x0.w, x1.x, x1.y, x1.z, x1.w};
#pragma unroll
            for (int r = 0; r < 8; r++) {
                acc[r][0] = fmaf(xr[r], w.x, acc[r][0]);
                acc[r][1] = fmaf(xr[r], w.y, acc[r][1]);
                acc[r][2] = fmaf(xr[r], w.z, acc[r][2]);
            }
        }
        __syncthreads();
    }

    if (f < F) {
#pragma unroll
        for (int r = 0; r < 8; r++) {
            int row = row0 + ry * 8 + r;
            if (row < n) {
                float gi = 1.f / (1.f + __expf(-acc[r][0]));
                float go = 1.f / (1.f + __expf(-acc[r][2]));
                float c = gi * tanhf(acc[r][1]);
                float h = go * tanhf(c);
                stv(&H[(size_t)row * F + f], fmaxf(h, 0.f));
            }
        }
    }
}

// ---------------- MFMA chebgate v2 (layer 2): LDS-staged A, fragment-linear B ----

template <int FIN, int K, int NT, int FPAD>
__global__ __launch_bounds__(256) void k_chebgate_mfma2(TP tp, const u16* __restrict__ Bp,
                                                        const float* __restrict__ b3,
                                                        u16* __restrict__ H, int n, int F,
                                                        int Hstride) {
    constexpr int NIT = K * FIN / 32;
    constexpr int CPR = FIN / 8;             // 16B chunks per A row
    constexpr int CSH = (CPR == 8) ? 3 : 2;
    constexpr int PANEL = 128 * FIN;         // u16 per tensor
    constexpr int IPT = (128 * CPR) / 256;   // gload16 per thread per tensor
    __shared__ __align__(16) u16 Alds[K * PANEL];

    const int tid = threadIdx.x;
    const int xb = blockIdx.x;
    const int wv = tid >> 6, lane = tid & 63;
    const int ln = lane & 15, lk = lane >> 4;
    const size_t panel_g = (size_t)xb * 128 * FIN;  // u16 offset into each tensor

    // ---- async stage: LDS linear, source pre-swizzled ----
#pragma unroll
    for (int t = 0; t < K; t++) {
        const u16* g = (const u16*)tp.p[t] + panel_g;
#pragma unroll
        for (int i = 0; i < IPT; i++) {
            int j0 = wv * (IPT * 64) + i * 64;   // wave-uniform chunk base
            int j = j0 + lane;
            int row = j >> CSH, c = j & (CPR - 1);
            int sc = (j & ~(CPR - 1)) | (c ^ (row & (CPR - 1)));
            gload16(g + (size_t)sc * 8, Alds + (size_t)t * PANEL + (size_t)j0 * 8);
        }
    }
    __syncthreads();

    const int r0 = xb * 128 + wv * 32;
    const u16* Bl = Bp + (size_t)lane * 8;

#pragma unroll 1
    for (int yb = 0; yb < NT; yb++) {
        f32x4 acc[2][2][3];
#pragma unroll
        for (int rt = 0; rt < 2; rt++)
#pragma unroll
            for (int s = 0; s < 2; s++)
#pragma unroll
                for (int g = 0; g < 3; g++) acc[rt][s][g] = (f32x4){0.f, 0.f, 0.f, 0.f};

#pragma unroll
        for (int it = 0; it < NIT; it++) {
            const int k0 = it * 32;
            const int t = k0 / FIN;
            const int a0 = k0 % FIN;
            bf16x8 af[2];
#pragma unroll
            for (int rt = 0; rt < 2; rt++) {
                int lrow = wv * 32 + rt * 16 + ln;
                int kc = (a0 >> 3) + lk;
                int kcs = kc ^ (lrow & (CPR - 1));
                af[rt] = *(const bf16x8*)(Alds + (size_t)t * PANEL + (size_t)lrow * FIN + kcs * 8);
            }
#pragma unroll
            for (int s = 0; s < 2; s++)
#pragma unroll
                for (int g = 0; g < 3; g++) {
                    int fi = (yb * NIT + it) * 6 + s * 3 + g;
                    bf16x8 bf = *(const bf16x8*)(Bl + (size_t)fi * 512);
#pragma unroll
                    for (int rt = 0; rt < 2; rt++)
                        acc[rt][s][g] = __builtin_amdgcn_mfma_f32_16x16x32_bf16(
                            af[rt], bf, acc[rt][s][g], 0, 0, 0);
                }
        }

        const int f0 = yb * 32;
#pragma unroll
        for (int s = 0; s < 2; s++) {
            int fcol = f0 + s * 16 + ln;
            if (fcol >= F) continue;
            float bi = b3[0 * FPAD + fcol];
            float bc = b3[1 * FPAD + fcol];
            float bo = b3[2 * FPAD + fcol];
#pragma unroll
            for (int rt = 0; rt < 2; rt++) {
#pragma unroll
                for (int reg = 0; reg < 4; reg++) {
                    int row = r0 + rt * 16 + lk * 4 + reg;
                    if (row < n) {
                        float gi = 1.f / (1.f + __expf(-(acc[rt][s][0][reg] + bi)));
                        float go = 1.f / (1.f + __expf(-(acc[rt][s][2][reg] + bo)));
                        float c = gi * tanhf(acc[rt][s][1][reg] + bc);
                        float h = go * tanhf(c);
                        H[(size_t)row * Hstride + fcol] = f2bf(fmaxf(h, 0.f));
                    }
                }
            }
        }
    }
}

// ---------------- MFMA chebgate v2 + fused final projection (layer 3) ----------------

template <int FIN, int K, int NT, int FPAD>
__global__ __launch_bounds__(256) void k_chebgate_mfma_fused2(
    TP tp, const u16* __restrict__ Bp, const float* __restrict__ b3,
    const float* __restrict__ W2, float* __restrict__ part, int n, int F) {
    constexpr int NIT = K * FIN / 32;
    constexpr int CPR = FIN / 8;
    constexpr int CSH = (CPR == 8) ? 3 : 2;
    constexpr int PANEL = 128 * FIN;
    constexpr int IPT = (128 * CPR) / 256;
    __shared__ __align__(16) u16 Alds[K * PANEL];

    const int tid = threadIdx.x;
    const int xb = blockIdx.x;
    const int wv = tid >> 6, lane = tid & 63;
    const int ln = lane & 15, lk = lane >> 4;
    const size_t panel_g = (size_t)xb * 128 * FIN;

#pragma unroll
    for (int t = 0; t < K; t++) {
        const u16* g = (const u16*)tp.p[t] + panel_g;
#pragma unroll
        for (int i = 0; i < IPT; i++) {
            int j0 = wv * (IPT * 64) + i * 64;
            int j = j0 + lane;
            int row = j >> CSH, c = j & (CPR - 1);
            int sc = (j & ~(CPR - 1)) | (c ^ (row & (CPR - 1)));
            gload16(g + (size_t)sc * 8, Alds + (size_t)t * PANEL + (size_t)j0 * 8);
        }
    }
    __syncthreads();

    const int r0 = xb * 128 + wv * 32;
    const u16* Bl = Bp + (size_t)lane * 8;

#pragma unroll 1
    for (int yb = 0; yb < NT; yb++) {
        f32x4 acc[2][2][3];
#pragma unroll
        for (int rt = 0; rt < 2; rt++)
#pragma unroll
            for (int s = 0; s < 2; s++)
#pragma unroll
                for (int g = 0; g < 3; g++) acc[rt][s][g] = (f32x4){0.f, 0.f, 0.f, 0.f};

#pragma unroll
        for (int it = 0; it < NIT; it++) {
            const int k0 = it * 32;
            const int t = k0 / FIN;
            const int a0 = k0 % FIN;
            bf16x8 af[2];
#pragma unroll
            for (int rt = 0; rt < 2; rt++) {
                int lrow = wv * 32 + rt * 16 + ln;
                int kc = (a0 >> 3) + lk;
                int kcs = kc ^ (lrow & (CPR - 1));
                af[rt] = *(const bf16x8*)(Alds + (size_t)t * PANEL + (size_t)lrow * FIN + kcs * 8);
            }
#pragma unroll
            for (int s = 0; s < 2; s++)
#pragma unroll
                for (int g = 0; g < 3; g++) {
                    int fi = (yb * NIT + it) * 6 + s * 3 + g;
                    bf16x8 bf = *(const bf16x8*)(Bl + (size_t)fi * 512);
#pragma unroll
                    for (int rt = 0; rt < 2; rt++)
                        acc[rt][s][g] = __builtin_amdgcn_mfma_f32_16x16x32_bf16(
                            af[rt], bf, acc[rt][s][g], 0, 0, 0);
                }
        }

        // epilogue + fused projection for this f-tile
        const int f0 = yb * 32;
        float p0[2][4], p1[2][4];
#pragma unroll
        for (int rt = 0; rt < 2; rt++)
#pragma unroll
            for (int reg = 0; reg < 4; reg++) { p0[rt][reg] = 0.f; p1[rt][reg] = 0.f; }

#pragma unroll
        for (int s = 0; s < 2; s++) {
            int fcol = f0 + s * 16 + ln;
            float w20 = fcol < F ? W2[fcol * 2 + 0] : 0.f;
            float w21 = fcol < F ? W2[fcol * 2 + 1] : 0.f;
            float bi = b3[0 * FPAD + fcol];
            float bc = b3[1 * FPAD + fcol];
            float bo = b3[2 * FPAD + fcol];
#pragma unroll
            for (int rt = 0; rt < 2; rt++) {
#pragma unroll
                for (int reg = 0; reg < 4; reg++) {
                    float gi = 1.f / (1.f + __expf(-(acc[rt][s][0][reg] + bi)));
                    float go = 1.f / (1.f + __expf(-(acc[rt][s][2][reg] + bo)));
                    float c = gi * tanhf(acc[rt][s][1][reg] + bc);
                    float h = fmaxf(go * tanhf(c), 0.f);
                    p0[rt][reg] = fmaf(h, w20, p0[rt][reg]);
                    p1[rt][reg] = fmaf(h, w21, p1[rt][reg]);
                }
            }
        }

#pragma unroll
        for (int rt = 0; rt < 2; rt++) {
#pragma unroll
            for (int reg = 0; reg < 4; reg++) {
                float v0 = p0[rt][reg], v1 = p1[rt][reg];
#pragma unroll
                for (int m = 1; m <= 8; m <<= 1) {
                    v0 += __shfl_xor(v0, m);
                    v1 += __shfl_xor(v1, m);
                }
                p0[rt][reg] = v0;
                p1[rt][reg] = v1;
            }
        }

        if (ln == 0) {
#pragma unroll
            for (int rt = 0; rt < 2; rt++) {
#pragma unroll
                for (int reg = 0; reg < 4; reg++) {
                    int row = r0 + rt * 16 + lk * 4 + reg;
                    if (row < n) {
                        float* pp = part + ((size_t)yb * n + row) * 2;
                        pp[0] = p0[rt][reg];
                        pp[1] = p1[rt][reg];
                    }
                }
            }
        }
    }
}

// ---------------- partial-sum + softmax ----------------
__global__ void k_smax(const float* __restrict__ part, const float* __restrict__ b,
                       float* __restrict__ out, int n, int ntiles) {
    int i = blockIdx.x * 256 + threadIdx.x;
    if (i >= n) return;
    float l0 = b[0], l1 = b[1];
    for (int t = 0; t < ntiles; t++) {
        const float* pp = part + ((size_t)t * n + i) * 2;
        l0 += pp[0];
        l1 += pp[1];
    }
    float m = fmaxf(l0, l1);
    float e0 = __expf(l0 - m), e1 = __expf(l1 - m);
    float s = 1.f / (e0 + e1);
    out[(size_t)i * 2 + 0] = e0 * s;
    out[(size_t)i * 2 + 1] = e1 * s;
}

// ---------------- weight/bias packing ----------------

__global__ void k_pack_w(const float* __restrict__ Wi, const float* __restrict__ Wc,
                         const float* __restrict__ Wo, float* __restrict__ Wp,
                         int KFIN, int F, int F4pad) {
    int idx = blockIdx.x * 256 + threadIdx.x;
    int tot = KFIN * F4pad;
    if (idx >= tot) return;
    int c = idx % F4pad;
    int ka = idx / F4pad;
    int f = c >> 2, g = c & 3;
    float v = 0.f;
    if (g < 3 && f < F) {
        const float* Wg = (g == 0) ? Wi : ((g == 1) ? Wc : Wo);
        v = Wg[(size_t)ka * F + f];
    }
    Wp[idx] = v;
}

__global__ void k_pack_b(const float* __restrict__ bxi, const float* __restrict__ bhi,
                         const float* __restrict__ bi, const float* __restrict__ bxc,
                         const float* __restrict__ bhc, const float* __restrict__ bc,
                         const float* __restrict__ bxo, const float* __restrict__ bho,
                         const float* __restrict__ bo, float* __restrict__ b4,
                         int F, int F4pad) {
    int idx = blockIdx.x * 256 + threadIdx.x;
    if (idx >= F4pad) return;
    int f = idx >> 2, g = idx & 3;
    float v = 0.f;
    if (g < 3 && f < F) {
        if (g == 0) v = bxi[f] + bhi[f] + bi[f];
        else if (g == 1) v = bxc[f] + bhc[f] + bc[f];
        else v = bxo[f] + bho[f] + bo[f];
    }
    b4[idx] = v;
}

// fragment-linear pack: Bp[yb][it][s*3+g][lane][8], lane=(lk<<4)|ln
// element (lane,j) = W_g[k = it*32 + lk*8 + j][fcol = yb*32 + s*16 + ln]
__global__ void k_pack_wf(const float* __restrict__ Wi, const float* __restrict__ Wc,
                          const float* __restrict__ Wo, u16* __restrict__ Bp,
                          int NIT, int Fin, int F, int NT) {
    int idx = blockIdx.x * 256 + threadIdx.x;
    int tot = NT * NIT * 6 * 512;
    if (idx >= tot) return;
    int frag = idx >> 9;
    int r = idx & 511;
    int lane = r >> 3, j = r & 7;
    int lk = lane >> 4, ln = lane & 15;
    int yb = frag / (NIT * 6);
    int q = frag % (NIT * 6);
    int it = q / 6, sg = q % 6;
    int s = sg / 3, g = sg % 3;
    int fcol = yb * 32 + s * 16 + ln;
    int k = it * 32 + lk * 8 + j;
    int t = k / Fin, a = k % Fin;
    float v = 0.f;
    if (fcol < F) {
        const float* Wg = (g == 0) ? Wi : ((g == 1) ? Wc : Wo);
        v = Wg[((size_t)t * Fin + a) * F + fcol];
    }
    Bp[idx] = f2bf(v);
}

__global__ void k_pack_b3(const float* __restrict__ bxi, const float* __restrict__ bhi,
                          const float* __restrict__ bi, const float* __restrict__ bxc,
                          const float* __restrict__ bhc, const float* __restrict__ bc,
                          const float* __restrict__ bxo, const float* __restrict__ bho,
                          const float* __restrict__ bo, float* __restrict__ b3,
                          int F, int FPAD) {
    int idx = blockIdx.x * 256 + threadIdx.x;
    if (idx >= 3 * FPAD) return;
    int g = idx / FPAD, f = idx % FPAD;
    float v = 0.f;
    if (f < F) {
        if (g == 0) v = bxi[f] + bhi[f] + bi[f];
        else if (g == 1) v = bxc[f] + bhc[f] + bc[f];
        else v = bxo[f] + bho[f] + bo[f];
    }
    b3[idx] = v;
}

__global__ void k_cvt(const float* __restrict__ x, u16* __restrict__ y, int n) {
    int i = blockIdx.x * 256 + threadIdx.x;
    if (i < n) y[i] = f2bf(x[i]);
}

// ---------------- launch ----------------

static inline size_t al(size_t x) { return (x + 255) & ~(size_t)255; }

extern "C" void kernel_launch(void* const* d_in, const int* in_sizes, int n_in,
                              void* d_out, int out_size, void* d_ws, size_t ws_size,
                              hipStream_t stream) {
    const float* X0 = (const float*)d_in[0];
    const int* ei = (const int*)d_in[1];
    const int N = in_sizes[0] / IN_CH;
    const int E = in_sizes[1] / 2;
    const int* src = ei;
    const int* dst = ei + E;

    // ---- workspace carve (~122 MB) ----
    char* p = (char*)d_ws;
    size_t off = 0;
    auto carve = [&](size_t bytes) -> char* { char* r = p + off; off += al(bytes); return r; };
    int* row_ptr  = (int*)carve((size_t)(N + 1) * 4);
    int* cnt      = (int*)carve((size_t)N * 4);
    int* cursor   = (int*)carve((size_t)N * 4);
    float* dinv   = (float*)carve((size_t)N * 4);
    int* bsum     = (int*)carve((size_t)1024 * 4);
    int* boff     = (int*)carve((size_t)1024 * 4);
    int* Cb       = (int*)carve((size_t)NB2MAX * PCH * 4);  // 256 KB
    int* seg      = (int*)carve((size_t)(NB2MAX + 1) * 4);
    Edge* edges   = (Edge*)carve((size_t)E * 8);
    const size_t S64 = al((size_t)N * 64 * 2);
    char* bufA    = carve(5 * S64);               // 64 MB
    char* bufB    = carve((size_t)N * 304);       // 30.4 MB
    float* Wp     = (float*)carve((size_t)48 * 128 * 4);
    float* b4     = (float*)carve((size_t)128 * 4);
    u16* Wt       = (u16*)carve((size_t)480 * 320 * 2);
    float* b3     = (float*)carve((size_t)480 * 4);
    (void)ws_size;

    u16* X0c  = (u16*)bufA;                                   // N x 10
    u16* T0_1 = (u16*)(bufA + al((size_t)N * 20));            // N x 10
    u16* H0   = (u16*)(bufA + S64);                           // N x 16
    u16* T1_1 = (u16*)(bufA + S64 + al((size_t)N * 32));      // N x 16
    u16* T1_2 = (u16*)(bufA + S64 + 2 * al((size_t)N * 32));  // N x 16
    u16* L2T[4];
    for (int t = 0; t < 4; t++) L2T[t] = (u16*)(bufB + t * al((size_t)N * 64));
    u16* L3T[5];
    for (int t = 0; t < 5; t++) L3T[t] = (u16*)(bufA + t * S64);
    float* part = (float*)bufB;                               // 5 x N x 2 fp32 (4 MB)
    // staging (dead before k_cvt): bufA start
    int* Sd = (int*)bufA;
    int* Ss = (int*)(bufA + al((size_t)E * 4));

    // ---- graph preprocessing: single-writer CSR ----
    int gN = (N + 255) / 256;
    int B = (N + 1023) / 1024;
    int nb2 = (N + 255) / 256;  // buckets of 256 nodes (nb2 <= NB2MAX)
    k_bcount<<<PCH, 256, 0, stream>>>(dst, Cb, E, nb2);
    k_boff<<<1, 512, 0, stream>>>(Cb, seg, nb2);
    k_stage<<<PCH, 256, 0, stream>>>(src, dst, Cb, Sd, Ss, E, nb2);
    k_bknt<<<nb2, 256, 0, stream>>>(Sd, seg, cnt, N);
    k_dinv<<<gN, 256, 0, stream>>>(cnt, dinv, N);
    k_bsum<<<B, 256, 0, stream>>>(cnt, bsum, N);
    k_bscan<<<1, 1024, 0, stream>>>(bsum, boff, row_ptr + N, B);
    k_write<<<B, 256, 0, stream>>>(cnt, boff, row_ptr, cursor, N);
    k_bscat<<<nb2, 256, 0, stream>>>(Sd, Ss, seg, row_ptr, dinv, edges, N);

    k_cvt<<<(N * IN_CH + 255) / 256, 256, 0, stream>>>(X0, X0c, N * IN_CH);

    dim3 gv(1, (N + 63) / 64);
    int rb = (N + 127) / 128;

    // spmv shapes: LPN = F/2 lanes per node
    dim3 bs5(5, 48);   int g5 = (N + 47) / 48;
    dim3 bs8(8, 32);   int g8 = (N + 31) / 32;
    dim3 bs16(16, 16); int g16 = (N + 15) / 16;
    dim3 bs32(32, 8);  int g32 = (N + 7) / 8;

    // ---- layer 0: VALU, K=2, Fin=10, F=16 ----
    {
        k_pack_w<<<(20 * 128 + 255) / 256, 256, 0, stream>>>(
            (const float*)d_in[2], (const float*)d_in[10], (const float*)d_in[14], Wp, 20, 16, 128);
        k_pack_b<<<1, 256, 0, stream>>>(
            (const float*)d_in[3], (const float*)d_in[4], (const float*)d_in[5],
            (const float*)d_in[11], (const float*)d_in[12], (const float*)d_in[13],
            (const float*)d_in[15], (const float*)d_in[16], (const float*)d_in[17], b4, 16, 128);
        k_spmv<10><<<g5, bs5, 0, stream>>>(X0c, nullptr, T0_1, row_ptr, edges, N, 1.f);
        TP tp; tp.p[0] = X0c; tp.p[1] = T0_1;
        k_chebgate<u16, 10, 2><<<gv, 256, 0, stream>>>(tp, Wp, b4, H0, N, 16, 128);
    }
    // ---- layer 1: VALU, K=3, Fin=16, F=32 ----
    {
        k_pack_w<<<(48 * 128 + 255) / 256, 256, 0, stream>>>(
            (const float*)d_in[18], (const float*)d_in[26], (const float*)d_in[30], Wp, 48, 32, 128);
        k_pack_b<<<1, 256, 0, stream>>>(
            (const float*)d_in[19], (const float*)d_in[20], (const float*)d_in[21],
            (const float*)d_in[27], (const float*)d_in[28], (const float*)d_in[29],
            (const float*)d_in[31], (const float*)d_in[32], (const float*)d_in[33], b4, 32, 128);
        k_spmv<16><<<g8, bs8, 0, stream>>>(H0, nullptr, T1_1, row_ptr, edges, N, 1.f);
        k_spmv<16><<<g8, bs8, 0, stream>>>(T1_1, H0, T1_2, row_ptr, edges, N, 2.f);
        TP tp; tp.p[0] = H0; tp.p[1] = T1_1; tp.p[2] = T1_2;
        k_chebgate<u16, 16, 3><<<gv, 256, 0, stream>>>(tp, Wp, b4, L2T[0], N, 32, 128);
    }
    // ---- layer 2: MFMA v2, K=4, Fin=32, F=64, NT=2 ----
    {
        // NIT = 4*32/32 = 4; Bp size = 2*4*6*512 halfwords = 48 KB
        k_pack_wf<<<(2 * 4 * 6 * 512 + 255) / 256, 256, 0, stream>>>(
            (const float*)d_in[34], (const float*)d_in[42], (const float*)d_in[46], Wt, 4, 32, 64, 2);
        k_pack_b3<<<1, 256, 0, stream>>>(
            (const float*)d_in[35], (const float*)d_in[36], (const float*)d_in[37],
            (const float*)d_in[43], (const float*)d_in[44], (const float*)d_in[45],
            (const float*)d_in[47], (const float*)d_in[48], (const float*)d_in[49], b3, 64, 64);
        k_spmv<32><<<g16, bs16, 0, stream>>>(L2T[0], nullptr, L2T[1], row_ptr, edges, N, 1.f);
        k_spmv<32><<<g16, bs16, 0, stream>>>(L2T[1], L2T[0], L2T[2], row_ptr, edges, N, 2.f);
        k_spmv<32><<<g16, bs16, 0, stream>>>(L2T[2], L2T[1], L2T[3], row_ptr, edges, N, 2.f);
        TP tp; for (int t = 0; t < 4; t++) tp.p[t] = L2T[t];
        k_chebgate_mfma2<32, 4, 2, 64><<<rb, 256, 0, stream>>>(tp, Wt, b3, L3T[0], N, 64, 64);
    }
    // ---- layer 3: MFMA v2 + fused final projection, K=5, Fin=64, F=152, NT=5 ----
    {
        // NIT = 5*64/32 = 10; Bp size = 5*10*6*512 halfwords = 300 KB
        k_pack_wf<<<(5 * 10 * 6 * 512 + 255) / 256, 256, 0, stream>>>(
            (const float*)d_in[50], (const float*)d_in[58], (const float*)d_in[62], Wt, 10, 64, 152, 5);
        k_pack_b3<<<2, 256, 0, stream>>>(
            (const float*)d_in[51], (const float*)d_in[52], (const float*)d_in[53],
            (const float*)d_in[59], (const float*)d_in[60], (const float*)d_in[61],
            (const float*)d_in[63], (const float*)d_in[64], (const float*)d_in[65], b3, 152, 160);
        k_spmv<64><<<g32, bs32, 0, stream>>>(L3T[0], nullptr, L3T[1], row_ptr, edges, N, 1.f);
        k_spmv<64><<<g32, bs32, 0, stream>>>(L3T[1], L3T[0], L3T[2], row_ptr, edges, N, 2.f);
        k_spmv<64><<<g32, bs32, 0, stream>>>(L3T[2], L3T[1], L3T[3], row_ptr, edges, N, 2.f);
        k_spmv<64><<<g32, bs32, 0, stream>>>(L3T[3], L3T[2], L3T[4], row_ptr, edges, N, 2.f);
        TP tp; for (int t = 0; t < 5; t++) tp.p[t] = L3T[t];
        k_chebgate_mfma_fused2<64, 5, 5, 160><<<rb, 256, 0, stream>>>(
            tp, Wt, b3, (const float*)d_in[66], part, N, 152);
    }

    k_smax<<<gN, 256, 0, stream>>>(part, (const float*)d_in[67], (float*)d_out, N, 5);
}

// Round 8
// 1011.748 us; speedup vs baseline: 1.1040x; 1.0215x over previous
//
#include <hip/hip_runtime.h>

// GConvLSTM single step x4 layers, H=C=0 => f-gate dead, peepholes dead.
// bf16 storage; parallel scan (R13); spmv unroll8 (R14).
// R16: XCD-congruent decode (L2 locality). R18: MFMA gates w/ async
// global_load_lds A-panels + fragment-linear B. R21: single-writer CSR build
// (counting sort) — scatter family off the critical path. New #1:
// k_chebgate_mfma_fused2 113us @ Occ 17.7% (80KB LDS => 2 blk x 4 waves =
// 2 waves/SIMD) with VALU epilogue (libm tanhf ~25 instr) outweighing MFMA
// (VALUBusy 26 vs MfmaUtil 10.6).
// NEW R22: (a) fused2 -> 512 threads / 8 waves x 16 rows, same LDS => 16
// waves/CU (4/SIMD), acc halves, __launch_bounds__(512,4);
// (b) fast tanh = 1 - 2/(exp(2x)+1) via __expf (overflow-exact) in all gates.

#define IN_CH 10
#define PCH 128     // staging chunks
#define NB2MAX 512  // max buckets (N<=131072)
typedef unsigned short u16;
typedef unsigned long long u64;
typedef short bf16x8 __attribute__((ext_vector_type(8)));
typedef float f32x4 __attribute__((ext_vector_type(4)));

struct __align__(8) Edge { int s; float w; };

__device__ __forceinline__ float bf2f(u16 u) { return __uint_as_float(((unsigned)u) << 16); }
__device__ __forceinline__ float lo16f(unsigned v) { return __uint_as_float(v << 16); }
__device__ __forceinline__ float hi16f(unsigned v) { return __uint_as_float(v & 0xffff0000u); }
__device__ __forceinline__ u16 f2bf(float f) {
    unsigned x = __float_as_uint(f);
    return (u16)((x + 0x7fff + ((x >> 16) & 1)) >> 16);  // RNE
}
__device__ __forceinline__ float ldv(const float* p) { return *p; }
__device__ __forceinline__ float ldv(const u16* p) { return bf2f(*p); }
__device__ __forceinline__ void stv(float* p, float v) { *p = v; }
__device__ __forceinline__ void stv(u16* p, float v) { *p = f2bf(v); }

// fast tanh: 1 - 2/(e^{2x}+1). x=+inf -> 1, x=-inf -> -1 (exact), ~6 instr.
__device__ __forceinline__ float ftanh(float x) {
    float t = __expf(2.f * x);
    return 1.f - 2.f / (t + 1.f);
}

// async global->LDS, 16B per lane. l must be wave-uniform; HW adds lane*16.
__device__ __forceinline__ void gload16(const u16* g, u16* l) {
    __builtin_amdgcn_global_load_lds(
        (const __attribute__((address_space(1))) unsigned*)(const void*)g,
        (__attribute__((address_space(3))) unsigned*)(void*)l, 16, 0, 0);
}

// ---------------- graph preprocessing: single-writer CSR build ----------------
// bucket = node >> 8 (256 nodes per bucket)

__global__ __launch_bounds__(256) void k_bcount(const int* __restrict__ dst,
                                                int* __restrict__ C, int e, int nb2) {
    __shared__ int sh[NB2MAX];
    const int p = blockIdx.x;
    for (int i = threadIdx.x; i < nb2; i += 256) sh[i] = 0;
    __syncthreads();
    const int chunk = (e + PCH - 1) / PCH;
    const int e0 = p * chunk, e1 = min(e0 + chunk, e);
    for (int i = e0 + threadIdx.x; i < e1; i += 256)
        atomicAdd(&sh[dst[i] >> 8], 1);
    __syncthreads();
    for (int b = threadIdx.x; b < nb2; b += 256) C[b * PCH + p] = sh[b];
}

__global__ __launch_bounds__(512) void k_boff(int* __restrict__ C, int* __restrict__ seg,
                                              int nb2) {
    __shared__ int sh[512];
    const int t = threadIdx.x;
    int tot = 0;
    if (t < nb2) {
        int* Cb = C + (size_t)t * PCH;
        int run = 0;
#pragma unroll 4
        for (int p = 0; p < PCH; p++) { int v = Cb[p]; Cb[p] = run; run += v; }
        tot = run;
    }
    sh[t] = tot;
    __syncthreads();
    for (int off = 1; off < 512; off <<= 1) {
        int x = (t >= off) ? sh[t - off] : 0;
        __syncthreads();
        sh[t] += x;
        __syncthreads();
    }
    const int base = sh[t] - tot;  // exclusive
    if (t < nb2) {
        seg[t] = base;
        int* Cb = C + (size_t)t * PCH;
#pragma unroll 4
        for (int p = 0; p < PCH; p++) Cb[p] += base;
        if (t == nb2 - 1) seg[nb2] = base + tot;
    }
}

__global__ __launch_bounds__(256) void k_stage(const int* __restrict__ src,
                                               const int* __restrict__ dst,
                                               const int* __restrict__ C,
                                               int* __restrict__ Sd, int* __restrict__ Ss,
                                               int e, int nb2) {
    __shared__ int cur[NB2MAX];
    const int p = blockIdx.x;
    for (int i = threadIdx.x; i < nb2; i += 256) cur[i] = C[(size_t)i * PCH + p];
    __syncthreads();
    const int chunk = (e + PCH - 1) / PCH;
    const int e0 = p * chunk, e1 = min(e0 + chunk, e);
    for (int i = e0 + threadIdx.x; i < e1; i += 256) {
        int d = dst[i], s = src[i];
        int pos = atomicAdd(&cur[d >> 8], 1);
        Sd[pos] = d;
        Ss[pos] = s;
    }
}

__global__ __launch_bounds__(256) void k_bknt(const int* __restrict__ Sd,
                                              const int* __restrict__ seg,
                                              int* __restrict__ cnt, int n) {
    __shared__ int sh[256];
    const int b = blockIdx.x;
    sh[threadIdx.x] = 0;
    __syncthreads();
    const int lo = seg[b], hi = seg[b + 1];
    for (int i = lo + threadIdx.x; i < hi; i += 256)
        atomicAdd(&sh[Sd[i] & 255], 1);
    __syncthreads();
    int node = b * 256 + threadIdx.x;
    if (node < n) cnt[node] = sh[threadIdx.x];
}

__global__ __launch_bounds__(256) void k_bscat(const int* __restrict__ Sd,
                                               const int* __restrict__ Ss,
                                               const int* __restrict__ seg,
                                               const int* __restrict__ row_ptr,
                                               const float* __restrict__ dinv,
                                               Edge* __restrict__ ed, int n) {
    __shared__ int cur[256];
    const int b = blockIdx.x;
    int node = b * 256 + threadIdx.x;
    cur[threadIdx.x] = node < n ? row_ptr[node] : 0;
    __syncthreads();
    const int lo = seg[b], hi = seg[b + 1];
    for (int i = lo + threadIdx.x; i < hi; i += 256) {
        int d = Sd[i], s = Ss[i];
        int pos = atomicAdd(&cur[d & 255], 1);  // LDS atomic
        float w = dinv[s] * dinv[d];
        u64 v = (u64)(unsigned)s | ((u64)__float_as_uint(w) << 32);
        *(u64*)&ed[pos] = v;
    }
}

__global__ void k_dinv(const int* __restrict__ cnt, float* __restrict__ dinv, int n) {
    int i = blockIdx.x * 256 + threadIdx.x;
    if (i < n) dinv[i] = cnt[i] > 0 ? rsqrtf((float)cnt[i]) : 0.f;
}

// ---- parallel scan: 1024 elems per 256-thread block ----

__global__ void k_bsum(const int* __restrict__ cnt, int* __restrict__ bsum, int n) {
    __shared__ int red[256];
    int t = threadIdx.x;
    int idx = blockIdx.x * 1024 + t * 4;
    int s = 0;
#pragma unroll
    for (int j = 0; j < 4; j++) s += (idx + j < n) ? cnt[idx + j] : 0;
    red[t] = s;
    __syncthreads();
    for (int off = 128; off > 0; off >>= 1) {
        if (t < off) red[t] += red[t + off];
        __syncthreads();
    }
    if (t == 0) bsum[blockIdx.x] = red[0];
}

__global__ __launch_bounds__(1024) void k_bscan(const int* __restrict__ bsum,
                                                int* __restrict__ boff,
                                                int* __restrict__ total_out, int B) {
    __shared__ int sh[1024];
    int t = threadIdx.x;
    int v = t < B ? bsum[t] : 0;
    sh[t] = v;
    __syncthreads();
    for (int off = 1; off < 1024; off <<= 1) {
        int x = (t >= off) ? sh[t - off] : 0;
        __syncthreads();
        sh[t] += x;
        __syncthreads();
    }
    if (t < B) boff[t] = sh[t] - v;  // exclusive
    if (t == B - 1) *total_out = sh[t];
}

__global__ void k_write(const int* __restrict__ cnt, const int* __restrict__ boff,
                        int* __restrict__ row_ptr, int* __restrict__ cursor, int n) {
    __shared__ int tsum[256];
    int t = threadIdx.x;
    int idx = blockIdx.x * 1024 + t * 4;
    int c[4];
    int s = 0;
#pragma unroll
    for (int j = 0; j < 4; j++) {
        c[j] = (idx + j < n) ? cnt[idx + j] : 0;
        s += c[j];
    }
    tsum[t] = s;
    __syncthreads();
    for (int off = 1; off < 256; off <<= 1) {
        int x = (t >= off) ? tsum[t - off] : 0;
        __syncthreads();
        tsum[t] += x;
        __syncthreads();
    }
    int run = boff[blockIdx.x] + tsum[t] - s;
#pragma unroll
    for (int j = 0; j < 4; j++) {
        if (idx + j < n) {
            row_ptr[idx + j] = run;
            cursor[idx + j] = run;
            run += c[j];
        }
    }
}

// ---------------- Cheb SpMV: full row, unroll x8 ----------------

template <int F>
__global__ void k_spmv(const u16* __restrict__ X, const u16* __restrict__ Tprev,
                       u16* __restrict__ Tout, const int* __restrict__ row_ptr,
                       const Edge* __restrict__ ed, int n, float scale) {
    int lane = threadIdx.x;  // [0, F/2)
    int node = blockIdx.x * blockDim.y + threadIdx.y;
    if (node >= n) return;
    int lo = row_ptr[node], hi = row_ptr[node + 1];
    const u16* Xc = X + 2 * lane;
    float a0[4] = {0.f, 0.f, 0.f, 0.f};
    float a1[4] = {0.f, 0.f, 0.f, 0.f};
    int e = lo;
    for (; e + 8 <= hi; e += 8) {
        Edge q[8];
#pragma unroll
        for (int j = 0; j < 8; j++) q[j] = ed[e + j];
        unsigned v[8];
#pragma unroll
        for (int j = 0; j < 8; j++)
            v[j] = *(const unsigned*)(Xc + (size_t)q[j].s * F);
#pragma unroll
        for (int j = 0; j < 8; j++) {
            a0[j & 3] = fmaf(q[j].w, lo16f(v[j]), a0[j & 3]);
            a1[j & 3] = fmaf(q[j].w, hi16f(v[j]), a1[j & 3]);
        }
    }
    for (; e + 4 <= hi; e += 4) {
        Edge q[4];
#pragma unroll
        for (int j = 0; j < 4; j++) q[j] = ed[e + j];
        unsigned v[4];
#pragma unroll
        for (int j = 0; j < 4; j++)
            v[j] = *(const unsigned*)(Xc + (size_t)q[j].s * F);
#pragma unroll
        for (int j = 0; j < 4; j++) {
            a0[j] = fmaf(q[j].w, lo16f(v[j]), a0[j]);
            a1[j] = fmaf(q[j].w, hi16f(v[j]), a1[j]);
        }
    }
    for (; e < hi; e++) {
        Edge q = ed[e];
        unsigned v = *(const unsigned*)(Xc + (size_t)q.s * F);
        a0[0] = fmaf(q.w, lo16f(v), a0[0]);
        a1[0] = fmaf(q.w, hi16f(v), a1[0]);
    }
    float v0 = -scale * ((a0[0] + a0[1]) + (a0[2] + a0[3]));
    float v1 = -scale * ((a1[0] + a1[1]) + (a1[2] + a1[3]));
    if (Tprev) {
        unsigned pv = *(const unsigned*)(Tprev + (size_t)node * F + 2 * lane);
        v0 -= lo16f(pv);
        v1 -= hi16f(pv);
    }
    *(unsigned*)(Tout + (size_t)node * F + 2 * lane) =
        (unsigned)f2bf(v0) | ((unsigned)f2bf(v1) << 16);
}

// ---------------- VALU chebgate (layers 0,1) ----------------
struct TP { const void* p[5]; };

template <typename ST, int FIN, int K>
__global__ __launch_bounds__(256) void k_chebgate(TP tp, const float* __restrict__ Wp,
                                                  const float* __restrict__ b4,
                                                  ST* __restrict__ H, int n, int F,
                                                  int F4pad) {
    __shared__ float As[FIN][68];
    __shared__ float Ws[FIN][128];
    const int tid = threadIdx.x;
    const int fx = tid & 31, ry = tid >> 5;
    const int row0 = blockIdx.y * 64;
    const int f0 = blockIdx.x * 32;
    const int f = f0 + fx;

    float acc[8][3];
    const float4 bv = *(const float4*)&b4[(size_t)f * 4];
#pragma unroll
    for (int r = 0; r < 8; r++) { acc[r][0] = bv.x; acc[r][1] = bv.y; acc[r][2] = bv.z; }

#pragma unroll
    for (int t = 0; t < K; t++) {
        const ST* T = (const ST*)tp.p[t];
        for (int idx = tid; idx < 64 * FIN; idx += 256) {
            int r = idx / FIN, a = idx - r * FIN;
            int rr = row0 + r;
            if (rr >= n) rr = n - 1;
            As[a][r] = ldv(&T[(size_t)rr * FIN + a]);
        }
        const float* Wt = Wp + (size_t)t * FIN * F4pad + (size_t)f0 * 4;
        for (int idx = tid; idx < FIN * 128; idx += 256) {
            int aa = idx >> 7, c = idx & 127;
            Ws[aa][c] = Wt[(size_t)aa * F4pad + c];
        }
        __syncthreads();
#pragma unroll 2
        for (int a = 0; a < FIN; a++) {
            const float4 w = *(const float4*)&Ws[a][fx * 4];
            const float4 x0 = *(const float4*)&As[a][ry * 8];
            const float4 x1 = *(const float4*)&As[a][ry * 8 + 4];
            const float xr[8] = {x0.x, x0.y, x0.z, x0.w, x1.x, x1.y, x1.z, x1.w};
#pragma unroll
            for (int r = 0; r < 8; r++) {
                acc[r][0] = fmaf(xr[r], w.x, acc[r][0]);
                acc[r][1] = fmaf(xr[r], w.y, acc[r][1]);
                acc[r][2] = fmaf(xr[r], w.z, acc[r][2]);
            }
        }
        __syncthreads();
    }

    if (f < F) {
#pragma unroll
        for (int r = 0; r < 8; r++) {
            int row = row0 + ry * 8 + r;
            if (row < n) {
                float gi = 1.f / (1.f + __expf(-acc[r][0]));
                float go = 1.f / (1.f + __expf(-acc[r][2]));
                float c = gi * ftanh(acc[r][1]);
                float h = go * ftanh(c);
                stv(&H[(size_t)row * F + f], fmaxf(h, 0.f));
            }
        }
    }
}

// ---------------- MFMA chebgate v2 (layer 2): LDS-staged A, fragment-linear B ----

template <int FIN, int K, int NT, int FPAD>
__global__ __launch_bounds__(256) void k_chebgate_mfma2(TP tp, const u16* __restrict__ Bp,
                                                        const float* __restrict__ b3,
                                                        u16* __restrict__ H, int n, int F,
                                                        int Hstride) {
    constexpr int NIT = K * FIN / 32;
    constexpr int CPR = FIN / 8;             // 16B chunks per A row
    constexpr int CSH = (CPR == 8) ? 3 : 2;
    constexpr int PANEL = 128 * FIN;         // u16 per tensor
    constexpr int IPT = (128 * CPR) / 256;   // gload16 per thread per tensor
    __shared__ __align__(16) u16 Alds[K * PANEL];

    const int tid = threadIdx.x;
    const int xb = blockIdx.x;
    const int wv = tid >> 6, lane = tid & 63;
    const int ln = lane & 15, lk = lane >> 4;
    const size_t panel_g = (size_t)xb * 128 * FIN;  // u16 offset into each tensor

#pragma unroll
    for (int t = 0; t < K; t++) {
        const u16* g = (const u16*)tp.p[t] + panel_g;
#pragma unroll
        for (int i = 0; i < IPT; i++) {
            int j0 = wv * (IPT * 64) + i * 64;   // wave-uniform chunk base
            int j = j0 + lane;
            int row = j >> CSH, c = j & (CPR - 1);
            int sc = (j & ~(CPR - 1)) | (c ^ (row & (CPR - 1)));
            gload16(g + (size_t)sc * 8, Alds + (size_t)t * PANEL + (size_t)j0 * 8);
        }
    }
    __syncthreads();

    const int r0 = xb * 128 + wv * 32;
    const u16* Bl = Bp + (size_t)lane * 8;

#pragma unroll 1
    for (int yb = 0; yb < NT; yb++) {
        f32x4 acc[2][2][3];
#pragma unroll
        for (int rt = 0; rt < 2; rt++)
#pragma unroll
            for (int s = 0; s < 2; s++)
#pragma unroll
                for (int g = 0; g < 3; g++) acc[rt][s][g] = (f32x4){0.f, 0.f, 0.f, 0.f};

#pragma unroll
        for (int it = 0; it < NIT; it++) {
            const int k0 = it * 32;
            const int t = k0 / FIN;
            const int a0 = k0 % FIN;
            bf16x8 af[2];
#pragma unroll
            for (int rt = 0; rt < 2; rt++) {
                int lrow = wv * 32 + rt * 16 + ln;
                int kc = (a0 >> 3) + lk;
                int kcs = kc ^ (lrow & (CPR - 1));
                af[rt] = *(const bf16x8*)(Alds + (size_t)t * PANEL + (size_t)lrow * FIN + kcs * 8);
            }
#pragma unroll
            for (int s = 0; s < 2; s++)
#pragma unroll
                for (int g = 0; g < 3; g++) {
                    int fi = (yb * NIT + it) * 6 + s * 3 + g;
                    bf16x8 bf = *(const bf16x8*)(Bl + (size_t)fi * 512);
#pragma unroll
                    for (int rt = 0; rt < 2; rt++)
                        acc[rt][s][g] = __builtin_amdgcn_mfma_f32_16x16x32_bf16(
                            af[rt], bf, acc[rt][s][g], 0, 0, 0);
                }
        }

        const int f0 = yb * 32;
#pragma unroll
        for (int s = 0; s < 2; s++) {
            int fcol = f0 + s * 16 + ln;
            if (fcol >= F) continue;
            float bi = b3[0 * FPAD + fcol];
            float bc = b3[1 * FPAD + fcol];
            float bo = b3[2 * FPAD + fcol];
#pragma unroll
            for (int rt = 0; rt < 2; rt++) {
#pragma unroll
                for (int reg = 0; reg < 4; reg++) {
                    int row = r0 + rt * 16 + lk * 4 + reg;
                    if (row < n) {
                        float gi = 1.f / (1.f + __expf(-(acc[rt][s][0][reg] + bi)));
                        float go = 1.f / (1.f + __expf(-(acc[rt][s][2][reg] + bo)));
                        float c = gi * ftanh(acc[rt][s][1][reg] + bc);
                        float h = go * ftanh(c);
                        H[(size_t)row * Hstride + fcol] = f2bf(fmaxf(h, 0.f));
                    }
                }
            }
        }
    }
}

// ---------------- MFMA chebgate v3 + fused final projection (layer 3) ----------------
// 512 threads / 8 waves x 16 rows: same 80KB LDS but 16 waves/CU (4/SIMD).

template <int FIN, int K, int NT, int FPAD>
__global__ __launch_bounds__(512, 4) void k_chebgate_mfma_fused2(
    TP tp, const u16* __restrict__ Bp, const float* __restrict__ b3,
    const float* __restrict__ W2, float* __restrict__ part, int n, int F) {
    constexpr int NIT = K * FIN / 32;
    constexpr int CPR = FIN / 8;
    constexpr int CSH = (CPR == 8) ? 3 : 2;
    constexpr int PANEL = 128 * FIN;
    constexpr int IPT = (128 * CPR) / 512;
    __shared__ __align__(16) u16 Alds[K * PANEL];

    const int tid = threadIdx.x;
    const int xb = blockIdx.x;
    const int wv = tid >> 6, lane = tid & 63;
    const int ln = lane & 15, lk = lane >> 4;
    const size_t panel_g = (size_t)xb * 128 * FIN;

#pragma unroll
    for (int t = 0; t < K; t++) {
        const u16* g = (const u16*)tp.p[t] + panel_g;
#pragma unroll
        for (int i = 0; i < IPT; i++) {
            int j0 = wv * (IPT * 64) + i * 64;
            int j = j0 + lane;
            int row = j >> CSH, c = j & (CPR - 1);
            int sc = (j & ~(CPR - 1)) | (c ^ (row & (CPR - 1)));
            gload16(g + (size_t)sc * 8, Alds + (size_t)t * PANEL + (size_t)j0 * 8);
        }
    }
    __syncthreads();

    const int r0 = xb * 128 + wv * 16;
    const int lrow = wv * 16 + ln;
    const int rmask = lrow & (CPR - 1);
    const u16* Bl = Bp + (size_t)lane * 8;

#pragma unroll 1
    for (int yb = 0; yb < NT; yb++) {
        f32x4 acc[2][3];
#pragma unroll
        for (int s = 0; s < 2; s++)
#pragma unroll
            for (int g = 0; g < 3; g++) acc[s][g] = (f32x4){0.f, 0.f, 0.f, 0.f};

#pragma unroll
        for (int it = 0; it < NIT; it++) {
            const int k0 = it * 32;
            const int t = k0 / FIN;
            const int a0 = k0 % FIN;
            int kcs = ((a0 >> 3) + lk) ^ rmask;
            bf16x8 af = *(const bf16x8*)(Alds + (size_t)t * PANEL + (size_t)lrow * FIN + kcs * 8);
#pragma unroll
            for (int s = 0; s < 2; s++)
#pragma unroll
                for (int g = 0; g < 3; g++) {
                    int fi = (yb * NIT + it) * 6 + s * 3 + g;
                    bf16x8 bf = *(const bf16x8*)(Bl + (size_t)fi * 512);
                    acc[s][g] = __builtin_amdgcn_mfma_f32_16x16x32_bf16(
                        af, bf, acc[s][g], 0, 0, 0);
                }
        }

        // epilogue + fused projection for this f-tile
        const int f0 = yb * 32;
        float p0[4], p1[4];
#pragma unroll
        for (int reg = 0; reg < 4; reg++) { p0[reg] = 0.f; p1[reg] = 0.f; }

#pragma unroll
        for (int s = 0; s < 2; s++) {
            int fcol = f0 + s * 16 + ln;
            float w20 = fcol < F ? W2[fcol * 2 + 0] : 0.f;
            float w21 = fcol < F ? W2[fcol * 2 + 1] : 0.f;
            float bi = b3[0 * FPAD + fcol];
            float bc = b3[1 * FPAD + fcol];
            float bo = b3[2 * FPAD + fcol];
#pragma unroll
            for (int reg = 0; reg < 4; reg++) {
                float gi = 1.f / (1.f + __expf(-(acc[s][0][reg] + bi)));
                float go = 1.f / (1.f + __expf(-(acc[s][2][reg] + bo)));
                float c = gi * ftanh(acc[s][1][reg] + bc);
                float h = fmaxf(go * ftanh(c), 0.f);
                p0[reg] = fmaf(h, w20, p0[reg]);
                p1[reg] = fmaf(h, w21, p1[reg]);
            }
        }

#pragma unroll
        for (int reg = 0; reg < 4; reg++) {
            float v0 = p0[reg], v1 = p1[reg];
#pragma unroll
            for (int m = 1; m <= 8; m <<= 1) {
                v0 += __shfl_xor(v0, m);
                v1 += __shfl_xor(v1, m);
            }
            p0[reg] = v0;
            p1[reg] = v1;
        }

        if (ln == 0) {
#pragma unroll
            for (int reg = 0; reg < 4; reg++) {
                int row = r0 + lk * 4 + reg;
                if (row < n) {
                    float* pp = part + ((size_t)yb * n + row) * 2;
                    pp[0] = p0[reg];
                    pp[1] = p1[reg];
                }
            }
        }
    }
}

// ---------------- partial-sum + softmax ----------------
__global__ void k_smax(const float* __restrict__ part, const float* __restrict__ b,
                       float* __restrict__ out, int n, int ntiles) {
    int i = blockIdx.x * 256 + threadIdx.x;
    if (i >= n) return;
    float l0 = b[0], l1 = b[1];
    for (int t = 0; t < ntiles; t++) {
        const float* pp = part + ((size_t)t * n + i) * 2;
        l0 += pp[0];
        l1 += pp[1];
    }
    float m = fmaxf(l0, l1);
    float e0 = __expf(l0 - m), e1 = __expf(l1 - m);
    float s = 1.f / (e0 + e1);
    out[(size_t)i * 2 + 0] = e0 * s;
    out[(size_t)i * 2 + 1] = e1 * s;
}

// ---------------- weight/bias packing ----------------

__global__ void k_pack_w(const float* __restrict__ Wi, const float* __restrict__ Wc,
                         const float* __restrict__ Wo, float* __restrict__ Wp,
                         int KFIN, int F, int F4pad) {
    int idx = blockIdx.x * 256 + threadIdx.x;
    int tot = KFIN * F4pad;
    if (idx >= tot) return;
    int c = idx % F4pad;
    int ka = idx / F4pad;
    int f = c >> 2, g = c & 3;
    float v = 0.f;
    if (g < 3 && f < F) {
        const float* Wg = (g == 0) ? Wi : ((g == 1) ? Wc : Wo);
        v = Wg[(size_t)ka * F + f];
    }
    Wp[idx] = v;
}

__global__ void k_pack_b(const float* __restrict__ bxi, const float* __restrict__ bhi,
                         const float* __restrict__ bi, const float* __restrict__ bxc,
                         const float* __restrict__ bhc, const float* __restrict__ bc,
                         const float* __restrict__ bxo, const float* __restrict__ bho,
                         const float* __restrict__ bo, float* __restrict__ b4,
                         int F, int F4pad) {
    int idx = blockIdx.x * 256 + threadIdx.x;
    if (idx >= F4pad) return;
    int f = idx >> 2, g = idx & 3;
    float v = 0.f;
    if (g < 3 && f < F) {
        if (g == 0) v = bxi[f] + bhi[f] + bi[f];
        else if (g == 1) v = bxc[f] + bhc[f] + bc[f];
        else v = bxo[f] + bho[f] + bo[f];
    }
    b4[idx] = v;
}

// fragment-linear pack: Bp[yb][it][s*3+g][lane][8], lane=(lk<<4)|ln
// element (lane,j) = W_g[k = it*32 + lk*8 + j][fcol = yb*32 + s*16 + ln]
__global__ void k_pack_wf(const float* __restrict__ Wi, const float* __restrict__ Wc,
                          const float* __restrict__ Wo, u16* __restrict__ Bp,
                          int NIT, int Fin, int F, int NT) {
    int idx = blockIdx.x * 256 + threadIdx.x;
    int tot = NT * NIT * 6 * 512;
    if (idx >= tot) return;
    int frag = idx >> 9;
    int r = idx & 511;
    int lane = r >> 3, j = r & 7;
    int lk = lane >> 4, ln = lane & 15;
    int yb = frag / (NIT * 6);
    int q = frag % (NIT * 6);
    int it = q / 6, sg = q % 6;
    int s = sg / 3, g = sg % 3;
    int fcol = yb * 32 + s * 16 + ln;
    int k = it * 32 + lk * 8 + j;
    int t = k / Fin, a = k % Fin;
    float v = 0.f;
    if (fcol < F) {
        const float* Wg = (g == 0) ? Wi : ((g == 1) ? Wc : Wo);
        v = Wg[((size_t)t * Fin + a) * F + fcol];
    }
    Bp[idx] = f2bf(v);
}

__global__ void k_pack_b3(const float* __restrict__ bxi, const float* __restrict__ bhi,
                          const float* __restrict__ bi, const float* __restrict__ bxc,
                          const float* __restrict__ bhc, const float* __restrict__ bc,
                          const float* __restrict__ bxo, const float* __restrict__ bho,
                          const float* __restrict__ bo, float* __restrict__ b3,
                          int F, int FPAD) {
    int idx = blockIdx.x * 256 + threadIdx.x;
    if (idx >= 3 * FPAD) return;
    int g = idx / FPAD, f = idx % FPAD;
    float v = 0.f;
    if (f < F) {
        if (g == 0) v = bxi[f] + bhi[f] + bi[f];
        else if (g == 1) v = bxc[f] + bhc[f] + bc[f];
        else v = bxo[f] + bho[f] + bo[f];
    }
    b3[idx] = v;
}

__global__ void k_cvt(const float* __restrict__ x, u16* __restrict__ y, int n) {
    int i = blockIdx.x * 256 + threadIdx.x;
    if (i < n) y[i] = f2bf(x[i]);
}

// ---------------- launch ----------------

static inline size_t al(size_t x) { return (x + 255) & ~(size_t)255; }

extern "C" void kernel_launch(void* const* d_in, const int* in_sizes, int n_in,
                              void* d_out, int out_size, void* d_ws, size_t ws_size,
                              hipStream_t stream) {
    const float* X0 = (const float*)d_in[0];
    const int* ei = (const int*)d_in[1];
    const int N = in_sizes[0] / IN_CH;
    const int E = in_sizes[1] / 2;
    const int* src = ei;
    const int* dst = ei + E;

    // ---- workspace carve (~122 MB) ----
    char* p = (char*)d_ws;
    size_t off = 0;
    auto carve = [&](size_t bytes) -> char* { char* r = p + off; off += al(bytes); return r; };
    int* row_ptr  = (int*)carve((size_t)(N + 1) * 4);
    int* cnt      = (int*)carve((size_t)N * 4);
    int* cursor   = (int*)carve((size_t)N * 4);
    float* dinv   = (float*)carve((size_t)N * 4);
    int* bsum     = (int*)carve((size_t)1024 * 4);
    int* boff     = (int*)carve((size_t)1024 * 4);
    int* Cb       = (int*)carve((size_t)NB2MAX * PCH * 4);  // 256 KB
    int* seg      = (int*)carve((size_t)(NB2MAX + 1) * 4);
    Edge* edges   = (Edge*)carve((size_t)E * 8);
    const size_t S64 = al((size_t)N * 64 * 2);
    char* bufA    = carve(5 * S64);               // 64 MB
    char* bufB    = carve((size_t)N * 304);       // 30.4 MB
    float* Wp     = (float*)carve((size_t)48 * 128 * 4);
    float* b4     = (float*)carve((size_t)128 * 4);
    u16* Wt       = (u16*)carve((size_t)480 * 320 * 2);
    float* b3     = (float*)carve((size_t)480 * 4);
    (void)ws_size;

    u16* X0c  = (u16*)bufA;                                   // N x 10
    u16* T0_1 = (u16*)(bufA + al((size_t)N * 20));            // N x 10
    u16* H0   = (u16*)(bufA + S64);                           // N x 16
    u16* T1_1 = (u16*)(bufA + S64 + al((size_t)N * 32));      // N x 16
    u16* T1_2 = (u16*)(bufA + S64 + 2 * al((size_t)N * 32));  // N x 16
    u16* L2T[4];
    for (int t = 0; t < 4; t++) L2T[t] = (u16*)(bufB + t * al((size_t)N * 64));
    u16* L3T[5];
    for (int t = 0; t < 5; t++) L3T[t] = (u16*)(bufA + t * S64);
    float* part = (float*)bufB;                               // 5 x N x 2 fp32 (4 MB)
    // staging (dead before k_cvt): bufA start
    int* Sd = (int*)bufA;
    int* Ss = (int*)(bufA + al((size_t)E * 4));

    // ---- graph preprocessing: single-writer CSR ----
    int gN = (N + 255) / 256;
    int B = (N + 1023) / 1024;
    int nb2 = (N + 255) / 256;  // buckets of 256 nodes (nb2 <= NB2MAX)
    k_bcount<<<PCH, 256, 0, stream>>>(dst, Cb, E, nb2);
    k_boff<<<1, 512, 0, stream>>>(Cb, seg, nb2);
    k_stage<<<PCH, 256, 0, stream>>>(src, dst, Cb, Sd, Ss, E, nb2);
    k_bknt<<<nb2, 256, 0, stream>>>(Sd, seg, cnt, N);
    k_dinv<<<gN, 256, 0, stream>>>(cnt, dinv, N);
    k_bsum<<<B, 256, 0, stream>>>(cnt, bsum, N);
    k_bscan<<<1, 1024, 0, stream>>>(bsum, boff, row_ptr + N, B);
    k_write<<<B, 256, 0, stream>>>(cnt, boff, row_ptr, cursor, N);
    k_bscat<<<nb2, 256, 0, stream>>>(Sd, Ss, seg, row_ptr, dinv, edges, N);

    k_cvt<<<(N * IN_CH + 255) / 256, 256, 0, stream>>>(X0, X0c, N * IN_CH);

    dim3 gv(1, (N + 63) / 64);
    int rb = (N + 127) / 128;

    // spmv shapes: LPN = F/2 lanes per node
    dim3 bs5(5, 48);   int g5 = (N + 47) / 48;
    dim3 bs8(8, 32);   int g8 = (N + 31) / 32;
    dim3 bs16(16, 16); int g16 = (N + 15) / 16;
    dim3 bs32(32, 8);  int g32 = (N + 7) / 8;

    // ---- layer 0: VALU, K=2, Fin=10, F=16 ----
    {
        k_pack_w<<<(20 * 128 + 255) / 256, 256, 0, stream>>>(
            (const float*)d_in[2], (const float*)d_in[10], (const float*)d_in[14], Wp, 20, 16, 128);
        k_pack_b<<<1, 256, 0, stream>>>(
            (const float*)d_in[3], (const float*)d_in[4], (const float*)d_in[5],
            (const float*)d_in[11], (const float*)d_in[12], (const float*)d_in[13],
            (const float*)d_in[15], (const float*)d_in[16], (const float*)d_in[17], b4, 16, 128);
        k_spmv<10><<<g5, bs5, 0, stream>>>(X0c, nullptr, T0_1, row_ptr, edges, N, 1.f);
        TP tp; tp.p[0] = X0c; tp.p[1] = T0_1;
        k_chebgate<u16, 10, 2><<<gv, 256, 0, stream>>>(tp, Wp, b4, H0, N, 16, 128);
    }
    // ---- layer 1: VALU, K=3, Fin=16, F=32 ----
    {
        k_pack_w<<<(48 * 128 + 255) / 256, 256, 0, stream>>>(
            (const float*)d_in[18], (const float*)d_in[26], (const float*)d_in[30], Wp, 48, 32, 128);
        k_pack_b<<<1, 256, 0, stream>>>(
            (const float*)d_in[19], (const float*)d_in[20], (const float*)d_in[21],
            (const float*)d_in[27], (const float*)d_in[28], (const float*)d_in[29],
            (const float*)d_in[31], (const float*)d_in[32], (const float*)d_in[33], b4, 32, 128);
        k_spmv<16><<<g8, bs8, 0, stream>>>(H0, nullptr, T1_1, row_ptr, edges, N, 1.f);
        k_spmv<16><<<g8, bs8, 0, stream>>>(T1_1, H0, T1_2, row_ptr, edges, N, 2.f);
        TP tp; tp.p[0] = H0; tp.p[1] = T1_1; tp.p[2] = T1_2;
        k_chebgate<u16, 16, 3><<<gv, 256, 0, stream>>>(tp, Wp, b4, L2T[0], N, 32, 128);
    }
    // ---- layer 2: MFMA v2, K=4, Fin=32, F=64, NT=2 ----
    {
        // NIT = 4*32/32 = 4; Bp size = 2*4*6*512 halfwords = 48 KB
        k_pack_wf<<<(2 * 4 * 6 * 512 + 255) / 256, 256, 0, stream>>>(
            (const float*)d_in[34], (const float*)d_in[42], (const float*)d_in[46], Wt, 4, 32, 64, 2);
        k_pack_b3<<<1, 256, 0, stream>>>(
            (const float*)d_in[35], (const float*)d_in[36], (const float*)d_in[37],
            (const float*)d_in[43], (const float*)d_in[44], (const float*)d_in[45],
            (const float*)d_in[47], (const float*)d_in[48], (const float*)d_in[49], b3, 64, 64);
        k_spmv<32><<<g16, bs16, 0, stream>>>(L2T[0], nullptr, L2T[1], row_ptr, edges, N, 1.f);
        k_spmv<32><<<g16, bs16, 0, stream>>>(L2T[1], L2T[0], L2T[2], row_ptr, edges, N, 2.f);
        k_spmv<32><<<g16, bs16, 0, stream>>>(L2T[2], L2T[1], L2T[3], row_ptr, edges, N, 2.f);
        TP tp; for (int t = 0; t < 4; t++) tp.p[t] = L2T[t];
        k_chebgate_mfma2<32, 4, 2, 64><<<rb, 256, 0, stream>>>(tp, Wt, b3, L3T[0], N, 64, 64);
    }
    // ---- layer 3: MFMA v3 + fused final projection, K=5, Fin=64, F=152, NT=5 ----
    {
        // NIT = 5*64/32 = 10; Bp size = 5*10*6*512 halfwords = 300 KB
        k_pack_wf<<<(5 * 10 * 6 * 512 + 255) / 256, 256, 0, stream>>>(
            (const float*)d_in[50], (const float*)d_in[58], (const float*)d_in[62], Wt, 10, 64, 152, 5);
        k_pack_b3<<<2, 256, 0, stream>>>(
            (const float*)d_in[51], (const float*)d_in[52], (const float*)d_in[53],
            (const float*)d_in[59], (const float*)d_in[60], (const float*)d_in[61],
            (const float*)d_in[63], (const float*)d_in[64], (const float*)d_in[65], b3, 152, 160);
        k_spmv<64><<<g32, bs32, 0, stream>>>(L3T[0], nullptr, L3T[1], row_ptr, edges, N, 1.f);
        k_spmv<64><<<g32, bs32, 0, stream>>>(L3T[1], L3T[0], L3T[2], row_ptr, edges, N, 2.f);
        k_spmv<64><<<g32, bs32, 0, stream>>>(L3T[2], L3T[1], L3T[3], row_ptr, edges, N, 2.f);
        k_spmv<64><<<g32, bs32, 0, stream>>>(L3T[3], L3T[2], L3T[4], row_ptr, edges, N, 2.f);
        TP tp; for (int t = 0; t < 5; t++) tp.p[t] = L3T[t];
        k_chebgate_mfma_fused2<64, 5, 5, 160><<<rb, 512, 0, stream>>>(
            tp, Wt, b3, (const float*)d_in[66], part, N, 152);
    }

    k_smax<<<gN, 256, 0, stream>>>(part, (const float*)d_in[67], (float*)d_out, N, 5);
}